// Round 5
// baseline (143.785 us; speedup 1.0000x reference)
//
#include <hip/hip_runtime.h>
#include <hip/hip_bf16.h>
#include <math.h>

// mLSTM chunked forward. Round 5: occupancy push.
// k_intra: 35.8 KB LDS (Cp read as global fragments, v staged post-barrier into union) -> 4 blocks/CU.
// k_state: hi-only kbar operand, fp32 nU via LDS partials -> 3 blocks/CU, half MFMA.
// B=4 H=8 T=4096 K=V=128, BT=64, NT=64.

#define LOG2E 1.4426950408889634f
constexpr int Bsz = 4, Hsz = 8, Tsz = 4096, Ksz = 128, Vsz = 128;
constexpr int BT = 64, NT = 64, BH = Bsz * Hsz;
constexpr float SCALE = 0.08838834764831845f; // 128^-0.5

typedef __attribute__((ext_vector_type(8))) short short8v;   // MFMA A/B frag (8 bf16)
typedef __attribute__((ext_vector_type(4))) float f32x4;     // MFMA C/D frag
typedef __attribute__((ext_vector_type(4))) unsigned short u16x4;
typedef __attribute__((ext_vector_type(8))) unsigned short u16x8;

__device__ inline float bf2f(unsigned short u) {
    union { unsigned int i; float f; } c; c.i = ((unsigned int)u) << 16; return c.f;
}
__device__ inline unsigned short f2bf(float f) {
    union { float f; unsigned int i; } c; c.f = f;
    unsigned int x = c.i;
    x += 0x7fffu + ((x >> 16) & 1u);      // round-to-nearest-even
    return (unsigned short)(x >> 16);
}

// ---------------- kernel 1: gate preprocessing per (bh, chunk) ----------------
__global__ __launch_bounds__(64) void k_gates(
    const float* __restrict__ ig, const float* __restrict__ fg,
    float* __restrict__ vecB, float* __restrict__ vecI, float* __restrict__ vecA,
    float* __restrict__ mintra, float* __restrict__ scaG, float* __restrict__ scaA)
{
    int c = blockIdx.x, bh = blockIdx.y, lane = threadIdx.x;
    int t = bh * Tsz + c * BT + lane;
    float f = fg[t];
    float ls = fminf(f, 0.f) - log1pf(expf(-fabsf(f)));  // stable log_sigmoid
    float vF = ls * LOG2E;
    float vI = ig[t] * LOG2E;
    float b = vF;
    #pragma unroll
    for (int off = 1; off < 64; off <<= 1) {
        float o = __shfl_up(b, off, 64);
        if (lane >= off) b += o;
    }
    float g = __shfl(b, 63, 64);
    float mi = vI - b;
    #pragma unroll
    for (int off = 1; off < 64; off <<= 1) {
        float o = __shfl_up(mi, off, 64);
        if (lane >= off) mi = fmaxf(mi, o);
    }
    float a = vI + g - b;
    vecB[t] = b; vecI[t] = vI; vecA[t] = a; mintra[t] = b + mi;
    float am = a;
    #pragma unroll
    for (int off = 32; off; off >>= 1) am = fmaxf(am, __shfl_xor(am, off, 64));
    if (lane == 0) { scaG[bh * NT + c] = g; scaA[bh * NT + c] = am; }
}

// ---------------- kernel 2: m stabilizer scan + per-chunk decay ----------------
__global__ __launch_bounds__(64) void k_mscan(
    const float* __restrict__ scaG, const float* __restrict__ scaA,
    float* __restrict__ mp, float* __restrict__ dec)
{
    int bh = blockIdx.x, lane = threadIdx.x;
    float g0 = scaG[bh * NT + lane];
    float a = g0, b = scaA[bh * NT + lane];
    #pragma unroll
    for (int off = 1; off < 64; off <<= 1) {
        float ap = __shfl_up(a, off, 64);
        float bp = __shfl_up(b, off, 64);
        if (lane >= off) { b = fmaxf(bp + a, b); a = ap + a; }
    }
    float m_incl = fmaxf(a, b);
    float m_prev = __shfl_up(m_incl, 1, 64);
    if (lane == 0) { m_prev = 0.f; mp[bh * (NT + 1)] = 0.f; }
    mp[bh * (NT + 1) + lane + 1] = m_incl;
    dec[bh * NT + lane] = exp2f(g0 + m_prev - m_incl);
}

// ---------------- kernel 3: U^T = v^T @ kbar (MFMA, hi-only operand; fp32 nU) ----------------
__global__ __launch_bounds__(256, 3) void k_state(
    const float* __restrict__ kg, const float* __restrict__ vg,
    const float* __restrict__ vecA, const float* __restrict__ mp,
    unsigned short* __restrict__ UT, float* __restrict__ nU)
{
    int c = blockIdx.x, bh = blockIdx.y, tid = threadIdx.x;
    int lane = tid & 63, wid = tid >> 6;
    int lrow = lane & 15, kgrp = lane >> 4;

    __shared__ __align__(16) unsigned short kThi[128][72];  // kbar^T [k][j]
    __shared__ __align__(16) unsigned short vTs[128][72];   // v^T    [v][j]
    __shared__ float nUp[128][17];                          // fp32 partial col-sums
    __shared__ float sfk[BT];

    size_t hb = (size_t)bh * Tsz + (size_t)c * BT;
    float mpn = mp[bh * (NT + 1) + c + 1];
    if (tid < BT) sfk[tid] = exp2f(vecA[hb + tid] - mpn);
    __syncthreads();

    int cb = tid & 15, jb = tid >> 4;     // col-block (of 4), j-block (of 4)
    #pragma unroll
    for (int p = 0; p < 2; ++p) {
        int c0 = p * 64 + cb * 4;
        float ka[4][4], va[4][4], s[4];
        #pragma unroll
        for (int x = 0; x < 4; ++x) {
            float4 kr = *(const float4*)(kg + (hb + jb * 4 + x) * Ksz + c0);
            float4 vr = *(const float4*)(vg + (hb + jb * 4 + x) * Vsz + c0);
            ka[x][0] = kr.x; ka[x][1] = kr.y; ka[x][2] = kr.z; ka[x][3] = kr.w;
            va[x][0] = vr.x; va[x][1] = vr.y; va[x][2] = vr.z; va[x][3] = vr.w;
            s[x] = sfk[jb * 4 + x];
        }
        #pragma unroll
        for (int y = 0; y < 4; ++y) {
            u16x4 h, w;
            float psum = 0.f;
            #pragma unroll
            for (int x = 0; x < 4; ++x) {
                float f = ka[x][y] * s[x];
                h[x] = f2bf(f);
                psum += f;
                w[x] = f2bf(va[x][y]);
            }
            *(u16x4*)&kThi[c0 + y][jb * 4] = h;
            *(u16x4*)&vTs[c0 + y][jb * 4] = w;
            nUp[c0 + y][jb] = psum;
        }
    }
    __syncthreads();

    // wave owns v-tiles {2*wid, 2*wid+1} x all 8 k-tiles
    f32x4 acc[2][8];
    #pragma unroll
    for (int vt = 0; vt < 2; ++vt)
        #pragma unroll
        for (int kt = 0; kt < 8; ++kt) acc[vt][kt] = (f32x4){0.f, 0.f, 0.f, 0.f};
    #pragma unroll
    for (int ks = 0; ks < 2; ++ks) {
        #pragma unroll
        for (int vt = 0; vt < 2; ++vt) {
            short8v af = *(const short8v*)&vTs[(wid * 2 + vt) * 16 + lrow][ks * 32 + kgrp * 8];
            #pragma unroll
            for (int kt = 0; kt < 8; ++kt) {
                short8v bh_ = *(const short8v*)&kThi[kt * 16 + lrow][ks * 32 + kgrp * 8];
                acc[vt][kt] = __builtin_amdgcn_mfma_f32_16x16x32_bf16(af, bh_, acc[vt][kt], 0, 0, 0);
            }
        }
    }
    unsigned short* Ub = UT + (size_t)(bh * NT + c) * (Ksz * Vsz);
    #pragma unroll
    for (int vt = 0; vt < 2; ++vt)
        #pragma unroll
        for (int kt = 0; kt < 8; ++kt)
            #pragma unroll
            for (int r = 0; r < 4; ++r) {
                int vc = (wid * 2 + vt) * 16 + kgrp * 4 + r;
                int kk = kt * 16 + lrow;
                Ub[(size_t)vc * Ksz + kk] = f2bf(acc[vt][kt][r]);
            }
    if (tid < Ksz) {
        float ssum = 0.f;
        #pragma unroll
        for (int j = 0; j < 16; ++j) ssum += nUp[tid][j];
        nU[(size_t)(bh * NT + c) * Ksz + tid] = ssum;
    }
}

// ---------------- kernel 4: normalizer scan ----------------
__global__ __launch_bounds__(128) void k_nscan(
    const float* __restrict__ nU, const float* __restrict__ dec, float* __restrict__ np)
{
    int bh = blockIdx.x, tid = threadIdx.x;
    float n = 0.f;
    size_t base = (size_t)bh * NT * Ksz + tid;
    for (int c = 0; c < NT; ++c) {
        np[base + (size_t)c * Ksz] = n;
        n = n * dec[bh * NT + c] + nU[base + (size_t)c * Ksz];
    }
}

// ---------------- kernel 5: elementwise state scan, in place (U -> Cp) ----------------
__global__ __launch_bounds__(256) void k_scan(
    unsigned short* __restrict__ UT, const float* __restrict__ dec)
{
    int s = blockIdx.x, bh = blockIdx.y, tid = threadIdx.x;
    __shared__ float decs[NT];
    if (tid < NT) decs[tid] = dec[bh * NT + tid];
    __syncthreads();
    int vc = s * 8 + (tid >> 5), k0 = (tid & 31) * 4;
    size_t base = (size_t)bh * NT * (Ksz * Vsz) + (size_t)vc * Ksz + k0;
    float C0 = 0.f, C1 = 0.f, C2 = 0.f, C3 = 0.f;
    for (int c = 0; c < NT; ++c) {
        size_t idx = base + (size_t)c * (Ksz * Vsz);
        u16x4 u = *(const u16x4*)(UT + idx);
        u16x4 w;
        w.x = f2bf(C0); w.y = f2bf(C1); w.z = f2bf(C2); w.w = f2bf(C3);
        *(u16x4*)(UT + idx) = w;
        float d = decs[c];
        C0 = C0 * d + bf2f(u.x); C1 = C1 * d + bf2f(u.y);
        C2 = C2 * d + bf2f(u.z); C3 = C3 * d + bf2f(u.w);
    }
}

// ---------------- kernel 6: intra + consumption + normalize ----------------
// 35.8 KB LDS: union{khi,klo | Sb,vT} + scalars -> 4 blocks/CU. Cp read as global fragments.
__global__ __launch_bounds__(256, 4) void k_intra(
    const float* __restrict__ qg, const float* __restrict__ kgl, const float* __restrict__ vg,
    const float* __restrict__ vecB, const float* __restrict__ vecI,
    const float* __restrict__ mintra, const float* __restrict__ mp,
    const float* __restrict__ np, const unsigned short* __restrict__ CpT,
    float* __restrict__ out)
{
    int c = blockIdx.x, bh = blockIdx.y, tid = threadIdx.x;
    int lane = tid & 63, wid = tid >> 6;
    int lrow = lane & 15, kgrp = lane >> 4;

    __shared__ __align__(16) unsigned short uA[64 * 136 * 2]; // union region (34816 B)
    __shared__ float rowf[BT], colf[BT], sfqs[BT], emcs[BT], denb[BT], npv[Ksz];

    auto khi = (unsigned short(*)[136])uA;              // phase A: k hi [64][136]
    auto klo = (unsigned short(*)[136])(uA + 64 * 136); // phase A: k lo
    auto Sb  = (unsigned short(*)[72])uA;               // phase B: S bf16 [64][72] (9216 B)
    auto vT  = (unsigned short(*)[72])(uA + 64 * 72);   // phase B: v^T [128][72] (18432 B)

    size_t hb = (size_t)bh * Tsz + (size_t)c * BT;
    float mpc = mp[bh * (NT + 1) + c];
    if (tid < BT) {
        float b = vecB[hb + tid];
        float mc = fmaxf(mpc + b, mintra[hb + tid]);
        rowf[tid] = SCALE * exp2f(b - mc);
        colf[tid] = exp2f(vecI[hb + tid] - b);
        sfqs[tid] = SCALE * exp2f(b + mpc - mc);
        emcs[tid] = exp2f(-mc);
    }
    if (tid < Ksz) npv[tid] = np[((size_t)bh * NT + c) * Ksz + tid];

    // stage k hi/lo
    const float4* k4 = (const float4*)(kgl + hb * Ksz);
    for (int e = tid; e < BT * Ksz / 4; e += 256) {
        int i = e >> 5, c4 = (e & 31) * 4;
        float4 kv = k4[e];
        u16x4 h, l;
        h.x = f2bf(kv.x); l.x = f2bf(kv.x - bf2f(h.x));
        h.y = f2bf(kv.y); l.y = f2bf(kv.y - bf2f(h.y));
        h.z = f2bf(kv.z); l.z = f2bf(kv.z - bf2f(h.z));
        h.w = f2bf(kv.w); l.w = f2bf(kv.w - bf2f(h.w));
        *(u16x4*)&khi[i][c4] = h; *(u16x4*)&klo[i][c4] = l;
    }
    // q rows (wave-local) into fp32 registers
    const float* qrow = qg + (hb + wid * 16 + lrow) * Ksz;
    float qf[4][8];
    #pragma unroll
    for (int ks = 0; ks < 4; ++ks) {
        float4 a = *(const float4*)(qrow + ks * 32 + kgrp * 8);
        float4 b = *(const float4*)(qrow + ks * 32 + kgrp * 8 + 4);
        qf[ks][0] = a.x; qf[ks][1] = a.y; qf[ks][2] = a.z; qf[ks][3] = a.w;
        qf[ks][4] = b.x; qf[ks][5] = b.y; qf[ks][6] = b.z; qf[ks][7] = b.w;
    }
    __syncthreads();

    // denominator inter part: qdot = sfq[row] * (q[row] . np), fp32
    float dot = 0.f;
    #pragma unroll
    for (int ks = 0; ks < 4; ++ks)
        #pragma unroll
        for (int x = 0; x < 8; ++x) dot += qf[ks][x] * npv[ks * 32 + kgrp * 8 + x];
    dot += __shfl_xor(dot, 16, 64);
    dot += __shfl_xor(dot, 32, 64);
    float qdot = sfqs[wid * 16 + lrow] * dot;

    // q -> hi/lo MFMA fragments
    short8v qh[4], ql[4];
    #pragma unroll
    for (int ks = 0; ks < 4; ++ks)
        #pragma unroll
        for (int x = 0; x < 8; ++x) {
            float f = qf[ks][x];
            unsigned short hh = f2bf(f);
            qh[ks][x] = (short)hh;
            ql[ks][x] = (short)f2bf(f - bf2f(hh));
        }

    // ---- Phase A: S = q k^T (3-way split, LDS k); inter = q @ Cp (global B-fragments) ----
    f32x4 accS[4];
    #pragma unroll
    for (int jt = 0; jt < 4; ++jt) accS[jt] = (f32x4){0.f, 0.f, 0.f, 0.f};
    #pragma unroll
    for (int ks = 0; ks < 4; ++ks) {
        #pragma unroll
        for (int jt = 0; jt < 4; ++jt) {
            if (jt <= wid) {
                short8v bh_ = *(const short8v*)&khi[jt * 16 + lrow][ks * 32 + kgrp * 8];
                short8v bl  = *(const short8v*)&klo[jt * 16 + lrow][ks * 32 + kgrp * 8];
                accS[jt] = __builtin_amdgcn_mfma_f32_16x16x32_bf16(qh[ks], bh_, accS[jt], 0, 0, 0);
                accS[jt] = __builtin_amdgcn_mfma_f32_16x16x32_bf16(ql[ks], bh_, accS[jt], 0, 0, 0);
                accS[jt] = __builtin_amdgcn_mfma_f32_16x16x32_bf16(qh[ks], bl,  accS[jt], 0, 0, 0);
            }
        }
    }
    const unsigned short* Cpb = CpT + ((size_t)bh * NT + c) * (Ksz * Vsz);
    f32x4 accC[8];
    #pragma unroll
    for (int vt = 0; vt < 8; ++vt) accC[vt] = (f32x4){0.f, 0.f, 0.f, 0.f};
    #pragma unroll
    for (int ks = 0; ks < 4; ++ks) {
        #pragma unroll
        for (int vt = 0; vt < 8; ++vt) {
            short8v bc = *(const short8v*)(Cpb + (size_t)(vt * 16 + lrow) * Ksz + ks * 32 + kgrp * 8);
            accC[vt] = __builtin_amdgcn_mfma_f32_16x16x32_bf16(qh[ks], bc, accC[vt], 0, 0, 0);
            accC[vt] = __builtin_amdgcn_mfma_f32_16x16x32_bf16(ql[ks], bc, accC[vt], 0, 0, 0);
        }
    }

    // mask + scale in regs; in-register rowsum; denominator
    float rsum[4] = {0.f, 0.f, 0.f, 0.f};
    unsigned short sreg[4][4];
    #pragma unroll
    for (int jt = 0; jt < 4; ++jt)
        #pragma unroll
        for (int r = 0; r < 4; ++r) {
            int i = wid * 16 + kgrp * 4 + r, j = jt * 16 + lrow;
            float val = (j <= i) ? accS[jt][r] * rowf[i] * colf[j] : 0.f;
            rsum[r] += val;
            sreg[jt][r] = f2bf(val);
        }
    #pragma unroll
    for (int r = 0; r < 4; ++r) {
        rsum[r] += __shfl_xor(rsum[r], 1, 64);
        rsum[r] += __shfl_xor(rsum[r], 2, 64);
        rsum[r] += __shfl_xor(rsum[r], 4, 64);
        rsum[r] += __shfl_xor(rsum[r], 8, 64);
    }
    float qd[4];
    #pragma unroll
    for (int r = 0; r < 4; ++r) qd[r] = __shfl(qdot, kgrp * 4 + r, 64);
    if (lrow == 0) {
        #pragma unroll
        for (int r = 0; r < 4; ++r) {
            int i = wid * 16 + kgrp * 4 + r;
            float den = qd[r] + rsum[r];
            denb[i] = 1.f / fmaxf(fabsf(den), emcs[i]);
        }
    }
    __syncthreads();   // all phase-A reads of khi/klo done -> union reuse safe

    // union writes: Sb (from sreg) + vT (fresh global v loads, register 4x4 transpose)
    #pragma unroll
    for (int jt = 0; jt < 4; ++jt)
        #pragma unroll
        for (int r = 0; r < 4; ++r)
            Sb[wid * 16 + kgrp * 4 + r][jt * 16 + lrow] = sreg[jt][r];
    {
        int vcb = tid & 15, jb = tid >> 4;
        #pragma unroll
        for (int p = 0; p < 2; ++p) {
            float t[4][4];
            #pragma unroll
            for (int x = 0; x < 4; ++x) {
                float4 r4 = *(const float4*)(vg + (hb + jb * 4 + x) * Vsz + p * 64 + vcb * 4);
                t[x][0] = r4.x; t[x][1] = r4.y; t[x][2] = r4.z; t[x][3] = r4.w;
            }
            #pragma unroll
            for (int y = 0; y < 4; ++y) {
                u16x4 w;
                #pragma unroll
                for (int x = 0; x < 4; ++x) w[x] = f2bf(t[x][y]);
                *(u16x4*)&vT[p * 64 + vcb * 4 + y][jb * 4] = w;
            }
        }
    }
    __syncthreads();

    // ---- Phase B: S @ v via MFMA ----
    f32x4 accV[8];
    #pragma unroll
    for (int vt = 0; vt < 8; ++vt) accV[vt] = (f32x4){0.f, 0.f, 0.f, 0.f};
    #pragma unroll
    for (int ks = 0; ks < 2; ++ks) {
        short8v as_ = *(const short8v*)&Sb[wid * 16 + lrow][ks * 32 + kgrp * 8];
        #pragma unroll
        for (int vt = 0; vt < 8; ++vt) {
            short8v bv = *(const short8v*)&vT[vt * 16 + lrow][ks * 32 + kgrp * 8];
            accV[vt] = __builtin_amdgcn_mfma_f32_16x16x32_bf16(as_, bv, accV[vt], 0, 0, 0);
        }
    }

    // ---- Phase C: combine + normalize + store ----
    size_t gb = hb * Vsz;
    #pragma unroll
    for (int vt = 0; vt < 8; ++vt)
        #pragma unroll
        for (int r = 0; r < 4; ++r) {
            int i = wid * 16 + kgrp * 4 + r, vc = vt * 16 + lrow;
            out[gb + (size_t)i * Vsz + vc] = (sfqs[i] * accC[vt][r] + accV[vt][r]) * denb[i];
        }
}

extern "C" void kernel_launch(void* const* d_in, const int* in_sizes, int n_in,
                              void* d_out, int out_size, void* d_ws, size_t ws_size,
                              hipStream_t stream) {
    const float* q  = (const float*)d_in[0];
    const float* k  = (const float*)d_in[1];
    const float* v  = (const float*)d_in[2];
    const float* ig = (const float*)d_in[3];
    const float* fg = (const float*)d_in[4];
    float* out = (float*)d_out;

    float* ws = (float*)d_ws;
    float* vecB   = ws;                       // BH*T
    float* vecI   = vecB + BH * Tsz;          // BH*T
    float* vecA   = vecI + BH * Tsz;          // BH*T
    float* mintra = vecA + BH * Tsz;          // BH*T
    float* scaG   = mintra + BH * Tsz;        // BH*NT
    float* scaA   = scaG + BH * NT;           // BH*NT
    float* dec    = scaA + BH * NT;           // BH*NT
    float* mp     = dec + BH * NT;            // BH*(NT+1)
    float* nU     = mp + BH * (NT + 1);       // BH*NT*K
    float* np     = nU + BH * NT * Ksz;       // BH*NT*K
    unsigned short* UT = (unsigned short*)(np + BH * NT * Ksz);  // BH*NT*K*V bf16 (in-place U->Cp)

    k_gates<<<dim3(NT, BH), 64, 0, stream>>>(ig, fg, vecB, vecI, vecA, mintra, scaG, scaA);
    k_mscan<<<dim3(BH), 64, 0, stream>>>(scaG, scaA, mp, dec);
    k_state<<<dim3(NT, BH), 256, 0, stream>>>(k, v, vecA, mp, UT, nU);
    k_nscan<<<dim3(BH), 128, 0, stream>>>(nU, dec, np);
    k_scan<<<dim3(16, BH), 256, 0, stream>>>(UT, dec);
    k_intra<<<dim3(NT, BH), 256, 0, stream>>>(q, k, v, vecB, vecI, mintra, mp, np, UT, out);
}

// Round 6
// 143.239 us; speedup vs baseline: 1.0038x; 1.0038x over previous
//
#include <hip/hip_runtime.h>
#include <hip/hip_bf16.h>
#include <math.h>

// mLSTM chunked forward. Round 6: k_intra phased-LDS reuse (4 blocks/CU, all MFMA
// operands in LDS, coalesced staging); bank-conflict-free transpose staging;
// ILP in the small scans. B=4 H=8 T=4096 K=V=128, BT=64, NT=64.

#define LOG2E 1.4426950408889634f
constexpr int Bsz = 4, Hsz = 8, Tsz = 4096, Ksz = 128, Vsz = 128;
constexpr int BT = 64, NT = 64, BH = Bsz * Hsz;
constexpr float SCALE = 0.08838834764831845f; // 128^-0.5

typedef __attribute__((ext_vector_type(8))) short short8v;   // MFMA A/B frag (8 bf16)
typedef __attribute__((ext_vector_type(4))) float f32x4;     // MFMA C/D frag
typedef __attribute__((ext_vector_type(4))) unsigned short u16x4;
typedef __attribute__((ext_vector_type(8))) unsigned short u16x8;

__device__ inline float bf2f(unsigned short u) {
    union { unsigned int i; float f; } c; c.i = ((unsigned int)u) << 16; return c.f;
}
__device__ inline unsigned short f2bf(float f) {
    union { float f; unsigned int i; } c; c.f = f;
    unsigned int x = c.i;
    x += 0x7fffu + ((x >> 16) & 1u);      // round-to-nearest-even
    return (unsigned short)(x >> 16);
}

// ---------------- kernel 1: gate preprocessing per (bh, chunk) ----------------
__global__ __launch_bounds__(64) void k_gates(
    const float* __restrict__ ig, const float* __restrict__ fg,
    float* __restrict__ vecB, float* __restrict__ vecI, float* __restrict__ vecA,
    float* __restrict__ mintra, float* __restrict__ scaG, float* __restrict__ scaA)
{
    int c = blockIdx.x, bh = blockIdx.y, lane = threadIdx.x;
    int t = bh * Tsz + c * BT + lane;
    float f = fg[t];
    float ls = fminf(f, 0.f) - log1pf(expf(-fabsf(f)));  // stable log_sigmoid
    float vF = ls * LOG2E;
    float vI = ig[t] * LOG2E;
    float b = vF;
    #pragma unroll
    for (int off = 1; off < 64; off <<= 1) {
        float o = __shfl_up(b, off, 64);
        if (lane >= off) b += o;
    }
    float g = __shfl(b, 63, 64);
    float mi = vI - b;
    #pragma unroll
    for (int off = 1; off < 64; off <<= 1) {
        float o = __shfl_up(mi, off, 64);
        if (lane >= off) mi = fmaxf(mi, o);
    }
    float a = vI + g - b;
    vecB[t] = b; vecI[t] = vI; vecA[t] = a; mintra[t] = b + mi;
    float am = a;
    #pragma unroll
    for (int off = 32; off; off >>= 1) am = fmaxf(am, __shfl_xor(am, off, 64));
    if (lane == 0) { scaG[bh * NT + c] = g; scaA[bh * NT + c] = am; }
}

// ---------------- kernel 2: m stabilizer scan + per-chunk decay ----------------
__global__ __launch_bounds__(64) void k_mscan(
    const float* __restrict__ scaG, const float* __restrict__ scaA,
    float* __restrict__ mp, float* __restrict__ dec)
{
    int bh = blockIdx.x, lane = threadIdx.x;
    float g0 = scaG[bh * NT + lane];
    float a = g0, b = scaA[bh * NT + lane];
    #pragma unroll
    for (int off = 1; off < 64; off <<= 1) {
        float ap = __shfl_up(a, off, 64);
        float bp = __shfl_up(b, off, 64);
        if (lane >= off) { b = fmaxf(bp + a, b); a = ap + a; }
    }
    float m_incl = fmaxf(a, b);
    float m_prev = __shfl_up(m_incl, 1, 64);
    if (lane == 0) { m_prev = 0.f; mp[bh * (NT + 1)] = 0.f; }
    mp[bh * (NT + 1) + lane + 1] = m_incl;
    dec[bh * NT + lane] = exp2f(g0 + m_prev - m_incl);
}

// ---------------- kernel 3: U^T = v^T @ kbar (MFMA, hi-only operand; fp32 nU) ----------------
__global__ __launch_bounds__(256, 3) void k_state(
    const float* __restrict__ kg, const float* __restrict__ vg,
    const float* __restrict__ vecA, const float* __restrict__ mp,
    unsigned short* __restrict__ UT, float* __restrict__ nU)
{
    int c = blockIdx.x, bh = blockIdx.y, tid = threadIdx.x;
    int lane = tid & 63, wid = tid >> 6;
    int lrow = lane & 15, kgrp = lane >> 4;

    __shared__ __align__(16) unsigned short kThi[128][72];  // kbar^T [k][j]
    __shared__ __align__(16) unsigned short vTs[128][72];   // v^T    [v][j]
    __shared__ float nUp[128][17];                          // fp32 partial col-sums
    __shared__ float sfk[BT];

    size_t hb = (size_t)bh * Tsz + (size_t)c * BT;
    float mpn = mp[bh * (NT + 1) + c + 1];
    if (tid < BT) sfk[tid] = exp2f(vecA[hb + tid] - mpn);
    __syncthreads();

    // transpose staging: jr = tid&15 (j-block) -> 16 lanes write 128B contiguous rows
    int jr = tid & 15, cb = tid >> 4;
    #pragma unroll
    for (int p = 0; p < 2; ++p) {
        int c0 = p * 64 + cb * 4;
        float ka[4][4], va[4][4], s[4];
        #pragma unroll
        for (int x = 0; x < 4; ++x) {
            float4 kr = *(const float4*)(kg + (hb + jr * 4 + x) * Ksz + c0);
            float4 vr = *(const float4*)(vg + (hb + jr * 4 + x) * Vsz + c0);
            ka[x][0] = kr.x; ka[x][1] = kr.y; ka[x][2] = kr.z; ka[x][3] = kr.w;
            va[x][0] = vr.x; va[x][1] = vr.y; va[x][2] = vr.z; va[x][3] = vr.w;
            s[x] = sfk[jr * 4 + x];
        }
        #pragma unroll
        for (int y = 0; y < 4; ++y) {
            u16x4 h, w;
            float psum = 0.f;
            #pragma unroll
            for (int x = 0; x < 4; ++x) {
                float f = ka[x][y] * s[x];
                h[x] = f2bf(f);
                psum += f;
                w[x] = f2bf(va[x][y]);
            }
            *(u16x4*)&kThi[c0 + y][jr * 4] = h;
            *(u16x4*)&vTs[c0 + y][jr * 4] = w;
            nUp[c0 + y][jr] = psum;
        }
    }
    __syncthreads();

    // wave owns v-tiles {2*wid, 2*wid+1} x all 8 k-tiles
    f32x4 acc[2][8];
    #pragma unroll
    for (int vt = 0; vt < 2; ++vt)
        #pragma unroll
        for (int kt = 0; kt < 8; ++kt) acc[vt][kt] = (f32x4){0.f, 0.f, 0.f, 0.f};
    #pragma unroll
    for (int ks = 0; ks < 2; ++ks) {
        #pragma unroll
        for (int vt = 0; vt < 2; ++vt) {
            short8v af = *(const short8v*)&vTs[(wid * 2 + vt) * 16 + lrow][ks * 32 + kgrp * 8];
            #pragma unroll
            for (int kt = 0; kt < 8; ++kt) {
                short8v bh_ = *(const short8v*)&kThi[kt * 16 + lrow][ks * 32 + kgrp * 8];
                acc[vt][kt] = __builtin_amdgcn_mfma_f32_16x16x32_bf16(af, bh_, acc[vt][kt], 0, 0, 0);
            }
        }
    }
    unsigned short* Ub = UT + (size_t)(bh * NT + c) * (Ksz * Vsz);
    #pragma unroll
    for (int vt = 0; vt < 2; ++vt)
        #pragma unroll
        for (int kt = 0; kt < 8; ++kt)
            #pragma unroll
            for (int r = 0; r < 4; ++r) {
                int vc = (wid * 2 + vt) * 16 + kgrp * 4 + r;
                int kk = kt * 16 + lrow;
                Ub[(size_t)vc * Ksz + kk] = f2bf(acc[vt][kt][r]);
            }
    if (tid < Ksz) {
        float ssum = 0.f;
        #pragma unroll
        for (int j = 0; j < 16; ++j) ssum += nUp[tid][j];
        nU[(size_t)(bh * NT + c) * Ksz + tid] = ssum;
    }
}

// ---------------- kernel 4: normalizer scan ----------------
__global__ __launch_bounds__(128) void k_nscan(
    const float* __restrict__ nU, const float* __restrict__ dec, float* __restrict__ np)
{
    int bh = blockIdx.x, tid = threadIdx.x;
    __shared__ float decs[NT];
    if (tid < NT) decs[tid] = dec[bh * NT + tid];
    __syncthreads();
    float n = 0.f;
    size_t base = (size_t)bh * NT * Ksz + tid;
    #pragma unroll 4
    for (int c = 0; c < NT; ++c) {
        float u = nU[base + (size_t)c * Ksz];   // address-independent: prefetchable
        np[base + (size_t)c * Ksz] = n;
        n = n * decs[c] + u;
    }
}

// ---------------- kernel 5: elementwise state scan, in place (U -> Cp) ----------------
__global__ __launch_bounds__(128) void k_scan(
    unsigned short* __restrict__ UT, const float* __restrict__ dec)
{
    int s = blockIdx.x, bh = blockIdx.y, tid = threadIdx.x;
    __shared__ float decs[NT];
    if (tid < NT) decs[tid] = dec[bh * NT + tid];
    __syncthreads();
    int vc = s * 4 + (tid >> 5), k0 = (tid & 31) * 4;
    size_t base = (size_t)bh * NT * (Ksz * Vsz) + (size_t)vc * Ksz + k0;
    float C0 = 0.f, C1 = 0.f, C2 = 0.f, C3 = 0.f;
    #pragma unroll 2
    for (int c = 0; c < NT; ++c) {
        size_t idx = base + (size_t)c * (Ksz * Vsz);
        u16x4 u = *(const u16x4*)(UT + idx);
        u16x4 w;
        w.x = f2bf(C0); w.y = f2bf(C1); w.z = f2bf(C2); w.w = f2bf(C3);
        *(u16x4*)(UT + idx) = w;
        float d = decs[c];
        C0 = C0 * d + bf2f(u.x); C1 = C1 * d + bf2f(u.y);
        C2 = C2 * d + bf2f(u.z); C3 = C3 * d + bf2f(u.w);
    }
}

// ---------------- kernel 6: intra + consumption + normalize ----------------
// One 34.8 KB LDS region reused across 3 phases: {khi,klo} -> {Sb,vT} -> {Cp}.
// 36.6 KB total -> 4 blocks/CU. All MFMA operands from LDS; staging coalesced.
__global__ __launch_bounds__(256, 4) void k_intra(
    const float* __restrict__ qg, const float* __restrict__ kgl, const float* __restrict__ vg,
    const float* __restrict__ vecB, const float* __restrict__ vecI,
    const float* __restrict__ mintra, const float* __restrict__ mp,
    const float* __restrict__ np, const unsigned short* __restrict__ CpT,
    float* __restrict__ out)
{
    int c = blockIdx.x, bh = blockIdx.y, tid = threadIdx.x;
    int lane = tid & 63, wid = tid >> 6;
    int lrow = lane & 15, kgrp = lane >> 4;

    __shared__ __align__(16) unsigned short R[17408];   // 34816 B, phase-shared
    __shared__ float rowf[BT], colf[BT], sfqs[BT], emcs[BT], denb[BT], npv[Ksz];

    auto khi = (unsigned short(*)[136])R;               // phase A: [64][136]
    auto klo = (unsigned short(*)[136])(R + 64 * 136);
    auto Sb  = (unsigned short(*)[72])R;                // phase B: [64][72]
    auto vT  = (unsigned short(*)[72])(R + 64 * 72);    //          [128][72]
    auto cps = (unsigned short(*)[136])R;               // phase C: [128][136]

    size_t hb = (size_t)bh * Tsz + (size_t)c * BT;
    float mpc = mp[bh * (NT + 1) + c];
    if (tid < BT) {
        float b = vecB[hb + tid];
        float mc = fmaxf(mpc + b, mintra[hb + tid]);
        rowf[tid] = SCALE * exp2f(b - mc);
        colf[tid] = exp2f(vecI[hb + tid] - b);
        sfqs[tid] = SCALE * exp2f(b + mpc - mc);
        emcs[tid] = exp2f(-mc);
    }
    if (tid < Ksz) npv[tid] = np[((size_t)bh * NT + c) * Ksz + tid];

    // ---- phase 1: stage k hi/lo; q -> regs; issue v prefetch ----
    const float4* k4 = (const float4*)(kgl + hb * Ksz);
    for (int e = tid; e < BT * Ksz / 4; e += 256) {
        int i = e >> 5, c4 = (e & 31) * 4;
        float4 kv = k4[e];
        u16x4 h, l;
        h.x = f2bf(kv.x); l.x = f2bf(kv.x - bf2f(h.x));
        h.y = f2bf(kv.y); l.y = f2bf(kv.y - bf2f(h.y));
        h.z = f2bf(kv.z); l.z = f2bf(kv.z - bf2f(h.z));
        h.w = f2bf(kv.w); l.w = f2bf(kv.w - bf2f(h.w));
        *(u16x4*)&khi[i][c4] = h; *(u16x4*)&klo[i][c4] = l;
    }
    const float* qrow = qg + (hb + wid * 16 + lrow) * Ksz;
    float qf[4][8];
    #pragma unroll
    for (int ks = 0; ks < 4; ++ks) {
        float4 a = *(const float4*)(qrow + ks * 32 + kgrp * 8);
        float4 b = *(const float4*)(qrow + ks * 32 + kgrp * 8 + 4);
        qf[ks][0] = a.x; qf[ks][1] = a.y; qf[ks][2] = a.z; qf[ks][3] = a.w;
        qf[ks][4] = b.x; qf[ks][5] = b.y; qf[ks][6] = b.z; qf[ks][7] = b.w;
    }
    // v prefetch (consumed in phase 3; in flight during S MFMAs)
    int jr = tid & 15, vcb = tid >> 4;
    float vpre[2][4][4];
    #pragma unroll
    for (int p = 0; p < 2; ++p)
        #pragma unroll
        for (int x = 0; x < 4; ++x) {
            float4 r4 = *(const float4*)(vg + (hb + jr * 4 + x) * Vsz + p * 64 + vcb * 4);
            vpre[p][x][0] = r4.x; vpre[p][x][1] = r4.y; vpre[p][x][2] = r4.z; vpre[p][x][3] = r4.w;
        }
    __syncthreads();

    // ---- phase 2: denominator inter part + S = q k^T (3-way split) ----
    float dot = 0.f;
    #pragma unroll
    for (int ks = 0; ks < 4; ++ks)
        #pragma unroll
        for (int x = 0; x < 8; ++x) dot += qf[ks][x] * npv[ks * 32 + kgrp * 8 + x];
    dot += __shfl_xor(dot, 16, 64);
    dot += __shfl_xor(dot, 32, 64);
    float qdot = sfqs[wid * 16 + lrow] * dot;

    short8v qh[4], ql[4];
    #pragma unroll
    for (int ks = 0; ks < 4; ++ks)
        #pragma unroll
        for (int x = 0; x < 8; ++x) {
            float f = qf[ks][x];
            unsigned short hh = f2bf(f);
            qh[ks][x] = (short)hh;
            ql[ks][x] = (short)f2bf(f - bf2f(hh));
        }

    f32x4 accS[4];
    #pragma unroll
    for (int jt = 0; jt < 4; ++jt) accS[jt] = (f32x4){0.f, 0.f, 0.f, 0.f};
    #pragma unroll
    for (int ks = 0; ks < 4; ++ks) {
        #pragma unroll
        for (int jt = 0; jt < 4; ++jt) {
            if (jt <= wid) {
                short8v bh_ = *(const short8v*)&khi[jt * 16 + lrow][ks * 32 + kgrp * 8];
                short8v bl  = *(const short8v*)&klo[jt * 16 + lrow][ks * 32 + kgrp * 8];
                accS[jt] = __builtin_amdgcn_mfma_f32_16x16x32_bf16(qh[ks], bh_, accS[jt], 0, 0, 0);
                accS[jt] = __builtin_amdgcn_mfma_f32_16x16x32_bf16(ql[ks], bh_, accS[jt], 0, 0, 0);
                accS[jt] = __builtin_amdgcn_mfma_f32_16x16x32_bf16(qh[ks], bl,  accS[jt], 0, 0, 0);
            }
        }
    }

    // mask + scale; in-register rowsum; denominator
    float rsum[4] = {0.f, 0.f, 0.f, 0.f};
    unsigned short sreg[4][4];
    #pragma unroll
    for (int jt = 0; jt < 4; ++jt)
        #pragma unroll
        for (int r = 0; r < 4; ++r) {
            int i = wid * 16 + kgrp * 4 + r, j = jt * 16 + lrow;
            float val = (j <= i) ? accS[jt][r] * rowf[i] * colf[j] : 0.f;
            rsum[r] += val;
            sreg[jt][r] = f2bf(val);
        }
    #pragma unroll
    for (int r = 0; r < 4; ++r) {
        rsum[r] += __shfl_xor(rsum[r], 1, 64);
        rsum[r] += __shfl_xor(rsum[r], 2, 64);
        rsum[r] += __shfl_xor(rsum[r], 4, 64);
        rsum[r] += __shfl_xor(rsum[r], 8, 64);
    }
    float qd[4];
    #pragma unroll
    for (int r = 0; r < 4; ++r) qd[r] = __shfl(qdot, kgrp * 4 + r, 64);
    if (lrow == 0) {
        #pragma unroll
        for (int r = 0; r < 4; ++r) {
            int i = wid * 16 + kgrp * 4 + r;
            float den = qd[r] + rsum[r];
            denb[i] = 1.f / fmaxf(fabsf(den), emcs[i]);
        }
    }
    __syncthreads();   // phase-A reads of khi/klo complete

    // ---- phase 3: write Sb + vT into reused region; issue Cp prefetch ----
    const u16x8* Cg = (const u16x8*)(CpT + ((size_t)bh * NT + c) * (Ksz * Vsz));
    u16x8 cpre[8];
    #pragma unroll
    for (int p2 = 0; p2 < 8; ++p2) cpre[p2] = Cg[tid + p2 * 256];  // in flight during PV

    #pragma unroll
    for (int jt = 0; jt < 4; ++jt)
        #pragma unroll
        for (int r = 0; r < 4; ++r)
            Sb[wid * 16 + kgrp * 4 + r][jt * 16 + lrow] = sreg[jt][r];
    #pragma unroll
    for (int p = 0; p < 2; ++p)
        #pragma unroll
        for (int y = 0; y < 4; ++y) {
            u16x4 w;
            #pragma unroll
            for (int x = 0; x < 4; ++x) w[x] = f2bf(vpre[p][x][y]);
            *(u16x4*)&vT[p * 64 + vcb * 4 + y][jr * 4] = w;
        }
    __syncthreads();

    // ---- phase 4: PV = S @ v via MFMA ----
    f32x4 accV[8];
    #pragma unroll
    for (int vt = 0; vt < 8; ++vt) accV[vt] = (f32x4){0.f, 0.f, 0.f, 0.f};
    #pragma unroll
    for (int ks = 0; ks < 2; ++ks) {
        short8v as_ = *(const short8v*)&Sb[wid * 16 + lrow][ks * 32 + kgrp * 8];
        #pragma unroll
        for (int vt = 0; vt < 8; ++vt) {
            short8v bv = *(const short8v*)&vT[vt * 16 + lrow][ks * 32 + kgrp * 8];
            accV[vt] = __builtin_amdgcn_mfma_f32_16x16x32_bf16(as_, bv, accV[vt], 0, 0, 0);
        }
    }
    __syncthreads();   // phase-B reads of Sb/vT complete

    // ---- phase 5: stage Cp into reused region (from prefetch regs) ----
    #pragma unroll
    for (int p2 = 0; p2 < 8; ++p2) {
        int idx = tid + p2 * 256;
        *(u16x8*)&cps[idx >> 4][(idx & 15) * 8] = cpre[p2];
    }
    __syncthreads();

    // ---- phase 6: inter = q @ Cp (2-way split) + combine + store ----
    f32x4 accC[8];
    #pragma unroll
    for (int vt = 0; vt < 8; ++vt) accC[vt] = (f32x4){0.f, 0.f, 0.f, 0.f};
    #pragma unroll
    for (int ks = 0; ks < 4; ++ks) {
        #pragma unroll
        for (int vt = 0; vt < 8; ++vt) {
            short8v bc = *(const short8v*)&cps[vt * 16 + lrow][ks * 32 + kgrp * 8];
            accC[vt] = __builtin_amdgcn_mfma_f32_16x16x32_bf16(qh[ks], bc, accC[vt], 0, 0, 0);
            accC[vt] = __builtin_amdgcn_mfma_f32_16x16x32_bf16(ql[ks], bc, accC[vt], 0, 0, 0);
        }
    }
    size_t gb = hb * Vsz;
    #pragma unroll
    for (int vt = 0; vt < 8; ++vt)
        #pragma unroll
        for (int r = 0; r < 4; ++r) {
            int i = wid * 16 + kgrp * 4 + r, vc = vt * 16 + lrow;
            out[gb + (size_t)i * Vsz + vc] = (sfqs[i] * accC[vt][r] + accV[vt][r]) * denb[i];
        }
}

extern "C" void kernel_launch(void* const* d_in, const int* in_sizes, int n_in,
                              void* d_out, int out_size, void* d_ws, size_t ws_size,
                              hipStream_t stream) {
    const float* q  = (const float*)d_in[0];
    const float* k  = (const float*)d_in[1];
    const float* v  = (const float*)d_in[2];
    const float* ig = (const float*)d_in[3];
    const float* fg = (const float*)d_in[4];
    float* out = (float*)d_out;

    float* ws = (float*)d_ws;
    float* vecB   = ws;                       // BH*T
    float* vecI   = vecB + BH * Tsz;          // BH*T
    float* vecA   = vecI + BH * Tsz;          // BH*T
    float* mintra = vecA + BH * Tsz;          // BH*T
    float* scaG   = mintra + BH * Tsz;        // BH*NT
    float* scaA   = scaG + BH * NT;           // BH*NT
    float* dec    = scaA + BH * NT;           // BH*NT
    float* mp     = dec + BH * NT;            // BH*(NT+1)
    float* nU     = mp + BH * (NT + 1);       // BH*NT*K
    float* np     = nU + BH * NT * Ksz;       // BH*NT*K
    unsigned short* UT = (unsigned short*)(np + BH * NT * Ksz);  // BH*NT*K*V bf16 (in-place U->Cp)

    k_gates<<<dim3(NT, BH), 64, 0, stream>>>(ig, fg, vecB, vecI, vecA, mintra, scaG, scaA);
    k_mscan<<<dim3(BH), 64, 0, stream>>>(scaG, scaA, mp, dec);
    k_state<<<dim3(NT, BH), 256, 0, stream>>>(k, v, vecA, mp, UT, nU);
    k_nscan<<<dim3(BH), 128, 0, stream>>>(nU, dec, np);
    k_scan<<<dim3(32, BH), 128, 0, stream>>>(UT, dec);
    k_intra<<<dim3(NT, BH), 256, 0, stream>>>(q, k, v, vecB, vecI, mintra, mp, np, UT, out);
}

// Round 7
// 125.881 us; speedup vs baseline: 1.1422x; 1.1379x over previous
//
#include <hip/hip_runtime.h>
#include <hip/hip_bf16.h>
#include <math.h>

// mLSTM chunked forward. Round 7: k_state coalesced staging + D[k][v] orientation
// (u16x4 stores); k_intra coalesced v-prefetch + XOR-swizzled vT; nscan merged into scan.
// B=4 H=8 T=4096 K=V=128, BT=64, NT=64.

#define LOG2E 1.4426950408889634f
constexpr int Bsz = 4, Hsz = 8, Tsz = 4096, Ksz = 128, Vsz = 128;
constexpr int BT = 64, NT = 64, BH = Bsz * Hsz;
constexpr float SCALE = 0.08838834764831845f; // 128^-0.5

typedef __attribute__((ext_vector_type(8))) short short8v;   // MFMA A/B frag (8 bf16)
typedef __attribute__((ext_vector_type(4))) float f32x4;     // MFMA C/D frag
typedef __attribute__((ext_vector_type(4))) unsigned short u16x4;
typedef __attribute__((ext_vector_type(8))) unsigned short u16x8;

__device__ inline float bf2f(unsigned short u) {
    union { unsigned int i; float f; } c; c.i = ((unsigned int)u) << 16; return c.f;
}
__device__ inline unsigned short f2bf(float f) {
    union { float f; unsigned int i; } c; c.f = f;
    unsigned int x = c.i;
    x += 0x7fffu + ((x >> 16) & 1u);      // round-to-nearest-even
    return (unsigned short)(x >> 16);
}

// ---------------- kernel 1: gate preprocessing per (bh, chunk) ----------------
__global__ __launch_bounds__(64) void k_gates(
    const float* __restrict__ ig, const float* __restrict__ fg,
    float* __restrict__ vecB, float* __restrict__ vecI, float* __restrict__ vecA,
    float* __restrict__ mintra, float* __restrict__ scaG, float* __restrict__ scaA)
{
    int c = blockIdx.x, bh = blockIdx.y, lane = threadIdx.x;
    int t = bh * Tsz + c * BT + lane;
    float f = fg[t];
    float ls = fminf(f, 0.f) - log1pf(expf(-fabsf(f)));  // stable log_sigmoid
    float vF = ls * LOG2E;
    float vI = ig[t] * LOG2E;
    float b = vF;
    #pragma unroll
    for (int off = 1; off < 64; off <<= 1) {
        float o = __shfl_up(b, off, 64);
        if (lane >= off) b += o;
    }
    float g = __shfl(b, 63, 64);
    float mi = vI - b;
    #pragma unroll
    for (int off = 1; off < 64; off <<= 1) {
        float o = __shfl_up(mi, off, 64);
        if (lane >= off) mi = fmaxf(mi, o);
    }
    float a = vI + g - b;
    vecB[t] = b; vecI[t] = vI; vecA[t] = a; mintra[t] = b + mi;
    float am = a;
    #pragma unroll
    for (int off = 32; off; off >>= 1) am = fmaxf(am, __shfl_xor(am, off, 64));
    if (lane == 0) { scaG[bh * NT + c] = g; scaA[bh * NT + c] = am; }
}

// ---------------- kernel 2: m stabilizer scan + per-chunk decay ----------------
__global__ __launch_bounds__(64) void k_mscan(
    const float* __restrict__ scaG, const float* __restrict__ scaA,
    float* __restrict__ mp, float* __restrict__ dec)
{
    int bh = blockIdx.x, lane = threadIdx.x;
    float g0 = scaG[bh * NT + lane];
    float a = g0, b = scaA[bh * NT + lane];
    #pragma unroll
    for (int off = 1; off < 64; off <<= 1) {
        float ap = __shfl_up(a, off, 64);
        float bp = __shfl_up(b, off, 64);
        if (lane >= off) { b = fmaxf(bp + a, b); a = ap + a; }
    }
    float m_incl = fmaxf(a, b);
    float m_prev = __shfl_up(m_incl, 1, 64);
    if (lane == 0) { m_prev = 0.f; mp[bh * (NT + 1)] = 0.f; }
    mp[bh * (NT + 1) + lane + 1] = m_incl;
    dec[bh * NT + lane] = exp2f(g0 + m_prev - m_incl);
}

// ---------------- kernel 3: U = kbar^T @ v (MFMA, D[k][v] orientation) ----------------
// Stores UT[v][k] with each lane writing u16x4 (4 consecutive k of one v-row).
__global__ __launch_bounds__(256, 3) void k_state(
    const float* __restrict__ kg, const float* __restrict__ vg,
    const float* __restrict__ vecA, const float* __restrict__ mp,
    unsigned short* __restrict__ UT, float* __restrict__ nU)
{
    int c = blockIdx.x, bh = blockIdx.y, tid = threadIdx.x;
    int lane = tid & 63, wid = tid >> 6;
    int lrow = lane & 15, kgrp = lane >> 4;

    __shared__ __align__(16) unsigned short kThi[128][72];  // kbar^T [k][j]
    __shared__ __align__(16) unsigned short vTs[128][72];   // v^T    [v][j]
    __shared__ float nUp[128][17];                          // fp32 partial col-sums

    size_t hb = (size_t)bh * Tsz + (size_t)c * BT;
    float mpn = mp[bh * (NT + 1) + c + 1];

    // coalesced staging: cb (col-block) fastest across lanes
    int cb = tid & 15, jr = tid >> 4;
    float s4[4];
    #pragma unroll
    for (int x = 0; x < 4; ++x) s4[x] = exp2f(vecA[hb + jr * 4 + x] - mpn);
    #pragma unroll
    for (int p = 0; p < 2; ++p) {
        int c0 = p * 64 + cb * 4;
        float ka[4][4], va[4][4];
        #pragma unroll
        for (int x = 0; x < 4; ++x) {
            float4 kr = *(const float4*)(kg + (hb + jr * 4 + x) * Ksz + c0);
            float4 vr = *(const float4*)(vg + (hb + jr * 4 + x) * Vsz + c0);
            ka[x][0] = kr.x; ka[x][1] = kr.y; ka[x][2] = kr.z; ka[x][3] = kr.w;
            va[x][0] = vr.x; va[x][1] = vr.y; va[x][2] = vr.z; va[x][3] = vr.w;
        }
        #pragma unroll
        for (int y = 0; y < 4; ++y) {
            u16x4 h, w;
            float psum = 0.f;
            #pragma unroll
            for (int x = 0; x < 4; ++x) {
                float f = ka[x][y] * s4[x];
                h[x] = f2bf(f);
                psum += f;
                w[x] = f2bf(va[x][y]);
            }
            *(u16x4*)&kThi[c0 + y][jr * 4] = h;
            *(u16x4*)&vTs[c0 + y][jr * 4] = w;
            nUp[c0 + y][jr] = psum;
        }
    }
    __syncthreads();

    // wave owns k-tiles {2*wid, 2*wid+1} x all 8 v-tiles; D[k][v]
    f32x4 acc[2][8];
    #pragma unroll
    for (int kt = 0; kt < 2; ++kt)
        #pragma unroll
        for (int vt = 0; vt < 8; ++vt) acc[kt][vt] = (f32x4){0.f, 0.f, 0.f, 0.f};
    #pragma unroll
    for (int ks = 0; ks < 2; ++ks) {
        #pragma unroll
        for (int kt = 0; kt < 2; ++kt) {
            short8v af = *(const short8v*)&kThi[(wid * 2 + kt) * 16 + lrow][ks * 32 + kgrp * 8];
            #pragma unroll
            for (int vt = 0; vt < 8; ++vt) {
                short8v bv = *(const short8v*)&vTs[vt * 16 + lrow][ks * 32 + kgrp * 8];
                acc[kt][vt] = __builtin_amdgcn_mfma_f32_16x16x32_bf16(af, bv, acc[kt][vt], 0, 0, 0);
            }
        }
    }
    // store: lane has 4 consecutive k (rows of D) at fixed v (col) -> u16x4
    unsigned short* Ub = UT + (size_t)(bh * NT + c) * (Ksz * Vsz);
    #pragma unroll
    for (int kt = 0; kt < 2; ++kt)
        #pragma unroll
        for (int vt = 0; vt < 8; ++vt) {
            int vc = vt * 16 + lrow;
            int k0 = (wid * 2 + kt) * 16 + kgrp * 4;
            u16x4 w;
            #pragma unroll
            for (int r = 0; r < 4; ++r) w[r] = f2bf(acc[kt][vt][r]);
            *(u16x4*)(Ub + (size_t)vc * Ksz + k0) = w;
        }
    if (tid < Ksz) {
        float ssum = 0.f;
        #pragma unroll
        for (int j = 0; j < 16; ++j) ssum += nUp[tid][j];
        nU[(size_t)(bh * NT + c) * Ksz + tid] = ssum;
    }
}

// ---------------- kernel 4: state scan (in place U->Cp) + fused normalizer scan ----------------
__global__ __launch_bounds__(128) void k_scan(
    unsigned short* __restrict__ UT, const float* __restrict__ dec,
    const float* __restrict__ nU, float* __restrict__ np)
{
    int s = blockIdx.x, bh = blockIdx.y, tid = threadIdx.x;
    __shared__ float decs[NT];
    if (tid < NT) decs[tid] = dec[bh * NT + tid];
    __syncthreads();
    if (s == 32) {   // fused normalizer scan: tid = k index
        float n = 0.f;
        size_t base = (size_t)bh * NT * Ksz + tid;
        #pragma unroll 4
        for (int c2 = 0; c2 < NT; ++c2) {
            float u = nU[base + (size_t)c2 * Ksz];
            np[base + (size_t)c2 * Ksz] = n;
            n = n * decs[c2] + u;
        }
        return;
    }
    int vc = s * 4 + (tid >> 5), k0 = (tid & 31) * 4;
    size_t base = (size_t)bh * NT * (Ksz * Vsz) + (size_t)vc * Ksz + k0;
    float C0 = 0.f, C1 = 0.f, C2 = 0.f, C3 = 0.f;
    #pragma unroll 4
    for (int c2 = 0; c2 < NT; ++c2) {
        size_t idx = base + (size_t)c2 * (Ksz * Vsz);
        u16x4 u = *(const u16x4*)(UT + idx);
        u16x4 w;
        w.x = f2bf(C0); w.y = f2bf(C1); w.z = f2bf(C2); w.w = f2bf(C3);
        *(u16x4*)(UT + idx) = w;
        float d = decs[c2];
        C0 = C0 * d + bf2f(u.x); C1 = C1 * d + bf2f(u.y);
        C2 = C2 * d + bf2f(u.z); C3 = C3 * d + bf2f(u.w);
    }
}

// ---------------- kernel 5: intra + consumption + normalize ----------------
// One 34.8 KB LDS region reused across 3 phases: {khi,klo} -> {Sb,vT-swizzled} -> {Cp}.
__global__ __launch_bounds__(256, 4) void k_intra(
    const float* __restrict__ qg, const float* __restrict__ kgl, const float* __restrict__ vg,
    const float* __restrict__ vecB, const float* __restrict__ vecI,
    const float* __restrict__ mintra, const float* __restrict__ mp,
    const float* __restrict__ np, const unsigned short* __restrict__ CpT,
    float* __restrict__ out)
{
    int c = blockIdx.x, bh = blockIdx.y, tid = threadIdx.x;
    int lane = tid & 63, wid = tid >> 6;
    int lrow = lane & 15, kgrp = lane >> 4;

    __shared__ __align__(16) unsigned short R[17408];   // 34816 B, phase-shared
    __shared__ float rowf[BT], colf[BT], sfqs[BT], emcs[BT], denb[BT], npv[Ksz];

    auto khi = (unsigned short(*)[136])R;               // phase A: [64][136]
    auto klo = (unsigned short(*)[136])(R + 64 * 136);
    auto Sb  = (unsigned short(*)[72])R;                // phase B: [64][72]
    unsigned short* vTf = R + 64 * 72;                  // phase B: v^T [128][64] XOR-swizzled
    auto cps = (unsigned short(*)[136])R;               // phase C: [128][136]

    size_t hb = (size_t)bh * Tsz + (size_t)c * BT;
    float mpc = mp[bh * (NT + 1) + c];
    if (tid < BT) {
        float b = vecB[hb + tid];
        float mc = fmaxf(mpc + b, mintra[hb + tid]);
        rowf[tid] = SCALE * exp2f(b - mc);
        colf[tid] = exp2f(vecI[hb + tid] - b);
        sfqs[tid] = SCALE * exp2f(b + mpc - mc);
        emcs[tid] = exp2f(-mc);
    }
    if (tid < Ksz) npv[tid] = np[((size_t)bh * NT + c) * Ksz + tid];

    // ---- phase 1: stage k hi/lo; q -> regs; issue v prefetch (coalesced) ----
    const float4* k4 = (const float4*)(kgl + hb * Ksz);
    for (int e = tid; e < BT * Ksz / 4; e += 256) {
        int i = e >> 5, c4 = (e & 31) * 4;
        float4 kv = k4[e];
        u16x4 h, l;
        h.x = f2bf(kv.x); l.x = f2bf(kv.x - bf2f(h.x));
        h.y = f2bf(kv.y); l.y = f2bf(kv.y - bf2f(h.y));
        h.z = f2bf(kv.z); l.z = f2bf(kv.z - bf2f(h.z));
        h.w = f2bf(kv.w); l.w = f2bf(kv.w - bf2f(h.w));
        *(u16x4*)&khi[i][c4] = h; *(u16x4*)&klo[i][c4] = l;
    }
    const float* qrow = qg + (hb + wid * 16 + lrow) * Ksz;
    float qf[4][8];
    #pragma unroll
    for (int ks = 0; ks < 4; ++ks) {
        float4 a = *(const float4*)(qrow + ks * 32 + kgrp * 8);
        float4 b = *(const float4*)(qrow + ks * 32 + kgrp * 8 + 4);
        qf[ks][0] = a.x; qf[ks][1] = a.y; qf[ks][2] = a.z; qf[ks][3] = a.w;
        qf[ks][4] = b.x; qf[ks][5] = b.y; qf[ks][6] = b.z; qf[ks][7] = b.w;
    }
    // v prefetch: vcb fastest -> coalesced 256B segments per row
    int vcb = tid & 15, jb = tid >> 4;
    float vpre[2][4][4];
    #pragma unroll
    for (int p = 0; p < 2; ++p)
        #pragma unroll
        for (int x = 0; x < 4; ++x) {
            float4 r4 = *(const float4*)(vg + (hb + jb * 4 + x) * Vsz + p * 64 + vcb * 4);
            vpre[p][x][0] = r4.x; vpre[p][x][1] = r4.y; vpre[p][x][2] = r4.z; vpre[p][x][3] = r4.w;
        }
    __syncthreads();

    // ---- phase 2: denominator inter part + S = q k^T (3-way split) ----
    float dot = 0.f;
    #pragma unroll
    for (int ks = 0; ks < 4; ++ks)
        #pragma unroll
        for (int x = 0; x < 8; ++x) dot += qf[ks][x] * npv[ks * 32 + kgrp * 8 + x];
    dot += __shfl_xor(dot, 16, 64);
    dot += __shfl_xor(dot, 32, 64);
    float qdot = sfqs[wid * 16 + lrow] * dot;

    short8v qh[4], ql[4];
    #pragma unroll
    for (int ks = 0; ks < 4; ++ks)
        #pragma unroll
        for (int x = 0; x < 8; ++x) {
            float f = qf[ks][x];
            unsigned short hh = f2bf(f);
            qh[ks][x] = (short)hh;
            ql[ks][x] = (short)f2bf(f - bf2f(hh));
        }

    f32x4 accS[4];
    #pragma unroll
    for (int jt = 0; jt < 4; ++jt) accS[jt] = (f32x4){0.f, 0.f, 0.f, 0.f};
    #pragma unroll
    for (int ks = 0; ks < 4; ++ks) {
        #pragma unroll
        for (int jt = 0; jt < 4; ++jt) {
            if (jt <= wid) {
                short8v bh_ = *(const short8v*)&khi[jt * 16 + lrow][ks * 32 + kgrp * 8];
                short8v bl  = *(const short8v*)&klo[jt * 16 + lrow][ks * 32 + kgrp * 8];
                accS[jt] = __builtin_amdgcn_mfma_f32_16x16x32_bf16(qh[ks], bh_, accS[jt], 0, 0, 0);
                accS[jt] = __builtin_amdgcn_mfma_f32_16x16x32_bf16(ql[ks], bh_, accS[jt], 0, 0, 0);
                accS[jt] = __builtin_amdgcn_mfma_f32_16x16x32_bf16(qh[ks], bl,  accS[jt], 0, 0, 0);
            }
        }
    }

    // mask + scale; in-register rowsum; denominator
    float rsum[4] = {0.f, 0.f, 0.f, 0.f};
    unsigned short sreg[4][4];
    #pragma unroll
    for (int jt = 0; jt < 4; ++jt)
        #pragma unroll
        for (int r = 0; r < 4; ++r) {
            int i = wid * 16 + kgrp * 4 + r, j = jt * 16 + lrow;
            float val = (j <= i) ? accS[jt][r] * rowf[i] * colf[j] : 0.f;
            rsum[r] += val;
            sreg[jt][r] = f2bf(val);
        }
    #pragma unroll
    for (int r = 0; r < 4; ++r) {
        rsum[r] += __shfl_xor(rsum[r], 1, 64);
        rsum[r] += __shfl_xor(rsum[r], 2, 64);
        rsum[r] += __shfl_xor(rsum[r], 4, 64);
        rsum[r] += __shfl_xor(rsum[r], 8, 64);
    }
    float qd[4];
    #pragma unroll
    for (int r = 0; r < 4; ++r) qd[r] = __shfl(qdot, kgrp * 4 + r, 64);
    if (lrow == 0) {
        #pragma unroll
        for (int r = 0; r < 4; ++r) {
            int i = wid * 16 + kgrp * 4 + r;
            float den = qd[r] + rsum[r];
            denb[i] = 1.f / fmaxf(fabsf(den), emcs[i]);
        }
    }
    __syncthreads();   // phase-A reads of khi/klo complete

    // ---- phase 3: write Sb + swizzled vT; issue Cp prefetch ----
    const u16x8* Cg = (const u16x8*)(CpT + ((size_t)bh * NT + c) * (Ksz * Vsz));
    u16x8 cpre[8];
    #pragma unroll
    for (int p2 = 0; p2 < 8; ++p2) cpre[p2] = Cg[tid + p2 * 256];  // in flight during PV

    #pragma unroll
    for (int jt = 0; jt < 4; ++jt)
        #pragma unroll
        for (int r = 0; r < 4; ++r)
            Sb[wid * 16 + kgrp * 4 + r][jt * 16 + lrow] = sreg[jt][r];
    #pragma unroll
    for (int p = 0; p < 2; ++p)
        #pragma unroll
        for (int y = 0; y < 4; ++y) {
            int row = p * 64 + vcb * 4 + y;
            int swzb = (jb * 8) ^ ((row & 7) << 4);   // byte offset, XOR-16B swizzle
            u16x4 w;
            #pragma unroll
            for (int x = 0; x < 4; ++x) w[x] = f2bf(vpre[p][x][y]);
            *(u16x4*)((char*)(vTf + row * 64) + swzb) = w;
        }
    __syncthreads();

    // ---- phase 4: PV = S @ v via MFMA (swizzled vT reads) ----
    f32x4 accV[8];
    #pragma unroll
    for (int vt = 0; vt < 8; ++vt) accV[vt] = (f32x4){0.f, 0.f, 0.f, 0.f};
    #pragma unroll
    for (int ks = 0; ks < 2; ++ks) {
        short8v as_ = *(const short8v*)&Sb[wid * 16 + lrow][ks * 32 + kgrp * 8];
        #pragma unroll
        for (int vt = 0; vt < 8; ++vt) {
            int row = vt * 16 + lrow;
            int swzb = ((ks * 64 + kgrp * 16)) ^ ((row & 7) << 4);
            short8v bv = *(const short8v*)((const char*)(vTf + row * 64) + swzb);
            accV[vt] = __builtin_amdgcn_mfma_f32_16x16x32_bf16(as_, bv, accV[vt], 0, 0, 0);
        }
    }
    __syncthreads();   // phase-B reads of Sb/vT complete

    // ---- phase 5: stage Cp into reused region (from prefetch regs) ----
    #pragma unroll
    for (int p2 = 0; p2 < 8; ++p2) {
        int idx = tid + p2 * 256;
        *(u16x8*)&cps[idx >> 4][(idx & 15) * 8] = cpre[p2];
    }
    __syncthreads();

    // ---- phase 6: inter = q @ Cp (2-way split) + combine + store ----
    f32x4 accC[8];
    #pragma unroll
    for (int vt = 0; vt < 8; ++vt) accC[vt] = (f32x4){0.f, 0.f, 0.f, 0.f};
    #pragma unroll
    for (int ks = 0; ks < 4; ++ks) {
        #pragma unroll
        for (int vt = 0; vt < 8; ++vt) {
            short8v bc = *(const short8v*)&cps[vt * 16 + lrow][ks * 32 + kgrp * 8];
            accC[vt] = __builtin_amdgcn_mfma_f32_16x16x32_bf16(qh[ks], bc, accC[vt], 0, 0, 0);
            accC[vt] = __builtin_amdgcn_mfma_f32_16x16x32_bf16(ql[ks], bc, accC[vt], 0, 0, 0);
        }
    }
    size_t gb = hb * Vsz;
    #pragma unroll
    for (int vt = 0; vt < 8; ++vt)
        #pragma unroll
        for (int r = 0; r < 4; ++r) {
            int i = wid * 16 + kgrp * 4 + r, vc = vt * 16 + lrow;
            out[gb + (size_t)i * Vsz + vc] = (sfqs[i] * accC[vt][r] + accV[vt][r]) * denb[i];
        }
}

extern "C" void kernel_launch(void* const* d_in, const int* in_sizes, int n_in,
                              void* d_out, int out_size, void* d_ws, size_t ws_size,
                              hipStream_t stream) {
    const float* q  = (const float*)d_in[0];
    const float* k  = (const float*)d_in[1];
    const float* v  = (const float*)d_in[2];
    const float* ig = (const float*)d_in[3];
    const float* fg = (const float*)d_in[4];
    float* out = (float*)d_out;

    float* ws = (float*)d_ws;
    float* vecB   = ws;                       // BH*T
    float* vecI   = vecB + BH * Tsz;          // BH*T
    float* vecA   = vecI + BH * Tsz;          // BH*T
    float* mintra = vecA + BH * Tsz;          // BH*T
    float* scaG   = mintra + BH * Tsz;        // BH*NT
    float* scaA   = scaG + BH * NT;           // BH*NT
    float* dec    = scaA + BH * NT;           // BH*NT
    float* mp     = dec + BH * NT;            // BH*(NT+1)
    float* nU     = mp + BH * (NT + 1);       // BH*NT*K
    float* np     = nU + BH * NT * Ksz;       // BH*NT*K
    unsigned short* UT = (unsigned short*)(np + BH * NT * Ksz);  // BH*NT*K*V bf16 (in-place U->Cp)

    k_gates<<<dim3(NT, BH), 64, 0, stream>>>(ig, fg, vecB, vecI, vecA, mintra, scaG, scaA);
    k_mscan<<<dim3(BH), 64, 0, stream>>>(scaG, scaA, mp, dec);
    k_state<<<dim3(NT, BH), 256, 0, stream>>>(k, v, vecA, mp, UT, nU);
    k_scan<<<dim3(33, BH), 128, 0, stream>>>(UT, dec, nU, np);
    k_intra<<<dim3(NT, BH), 256, 0, stream>>>(q, k, v, vecB, vecI, mintra, mp, np, UT, out);
}

// Round 8
// 119.817 us; speedup vs baseline: 1.2000x; 1.0506x over previous
//
#include <hip/hip_runtime.h>
#include <hip/hip_bf16.h>
#include <math.h>

// mLSTM chunked forward. Round 8: fragment-major flat UT layout (coalesced k_state
// stores, flat k_scan, two-b64 fragment reads in k_intra); HW v_cvt bf16 conversion;
// k_state 4 blocks/CU via shfl-reduced nU partials.
// B=4 H=8 T=4096 K=V=128, BT=64, NT=64.

#define LOG2E 1.4426950408889634f
constexpr int Bsz = 4, Hsz = 8, Tsz = 4096, Ksz = 128, Vsz = 128;
constexpr int BT = 64, NT = 64, BH = Bsz * Hsz;
constexpr float SCALE = 0.08838834764831845f; // 128^-0.5

typedef __attribute__((ext_vector_type(8))) short short8v;   // MFMA A/B frag (8 bf16)
typedef __attribute__((ext_vector_type(4))) float f32x4;     // MFMA C/D frag
typedef __attribute__((ext_vector_type(4))) unsigned short u16x4;
typedef __attribute__((ext_vector_type(8))) unsigned short u16x8;

__device__ inline float bf2f(unsigned short u) {
    union { unsigned int i; float f; } c; c.i = ((unsigned int)u) << 16; return c.f;
}
__device__ inline unsigned short f2bf(float f) {
    __hip_bfloat16 h = __float2bfloat16(f);            // HW v_cvt (RNE)
    union { __hip_bfloat16 b; unsigned short u; } cv; cv.b = h; return cv.u;
}

// ---------------- kernel 1: gate preprocessing per (bh, chunk) ----------------
__global__ __launch_bounds__(64) void k_gates(
    const float* __restrict__ ig, const float* __restrict__ fg,
    float* __restrict__ vecB, float* __restrict__ vecI, float* __restrict__ vecA,
    float* __restrict__ mintra, float* __restrict__ scaG, float* __restrict__ scaA)
{
    int c = blockIdx.x, bh = blockIdx.y, lane = threadIdx.x;
    int t = bh * Tsz + c * BT + lane;
    float f = fg[t];
    float ls = fminf(f, 0.f) - log1pf(expf(-fabsf(f)));  // stable log_sigmoid
    float vF = ls * LOG2E;
    float vI = ig[t] * LOG2E;
    float b = vF;
    #pragma unroll
    for (int off = 1; off < 64; off <<= 1) {
        float o = __shfl_up(b, off, 64);
        if (lane >= off) b += o;
    }
    float g = __shfl(b, 63, 64);
    float mi = vI - b;
    #pragma unroll
    for (int off = 1; off < 64; off <<= 1) {
        float o = __shfl_up(mi, off, 64);
        if (lane >= off) mi = fmaxf(mi, o);
    }
    float a = vI + g - b;
    vecB[t] = b; vecI[t] = vI; vecA[t] = a; mintra[t] = b + mi;
    float am = a;
    #pragma unroll
    for (int off = 32; off; off >>= 1) am = fmaxf(am, __shfl_xor(am, off, 64));
    if (lane == 0) { scaG[bh * NT + c] = g; scaA[bh * NT + c] = am; }
}

// ---------------- kernel 2: m stabilizer scan + per-chunk decay ----------------
__global__ __launch_bounds__(64) void k_mscan(
    const float* __restrict__ scaG, const float* __restrict__ scaA,
    float* __restrict__ mp, float* __restrict__ dec)
{
    int bh = blockIdx.x, lane = threadIdx.x;
    float g0 = scaG[bh * NT + lane];
    float a = g0, b = scaA[bh * NT + lane];
    #pragma unroll
    for (int off = 1; off < 64; off <<= 1) {
        float ap = __shfl_up(a, off, 64);
        float bp = __shfl_up(b, off, 64);
        if (lane >= off) { b = fmaxf(bp + a, b); a = ap + a; }
    }
    float m_incl = fmaxf(a, b);
    float m_prev = __shfl_up(m_incl, 1, 64);
    if (lane == 0) { m_prev = 0.f; mp[bh * (NT + 1)] = 0.f; }
    mp[bh * (NT + 1) + lane + 1] = m_incl;
    dec[bh * NT + lane] = exp2f(g0 + m_prev - m_incl);
}

// ---------------- kernel 3: U = kbar^T @ v, fragment-major flat output ----------------
// flatU[((ktile*8+vt)*64+lane)*4+r] = U[k=ktile*16+(lane>>4)*4+r][v=vt*16+(lane&15)].
// Wave stores are 512B-contiguous.
__global__ __launch_bounds__(256, 4) void k_state(
    const float* __restrict__ kg, const float* __restrict__ vg,
    const float* __restrict__ vecA, const float* __restrict__ mp,
    unsigned short* __restrict__ UT, float* __restrict__ nU)
{
    int c = blockIdx.x, bh = blockIdx.y, tid = threadIdx.x;
    int lane = tid & 63, wid = tid >> 6;
    int lrow = lane & 15, kgrp = lane >> 4;

    __shared__ __align__(16) unsigned short kThi[128][72];  // kbar^T [k][j]
    __shared__ __align__(16) unsigned short vTs[128][72];   // v^T    [v][j]
    __shared__ float nUp[128][5];                           // per-wave fp32 partials

    size_t hb = (size_t)bh * Tsz + (size_t)c * BT;
    float mpn = mp[bh * (NT + 1) + c + 1];

    int cb = tid & 15, jr = tid >> 4;   // cb: col-block (coalesced), jr: j-block
    float s4[4];
    #pragma unroll
    for (int x = 0; x < 4; ++x) s4[x] = exp2f(vecA[hb + jr * 4 + x] - mpn);
    #pragma unroll
    for (int p = 0; p < 2; ++p) {
        int c0 = p * 64 + cb * 4;
        float ka[4][4], va[4][4];
        #pragma unroll
        for (int x = 0; x < 4; ++x) {
            float4 kr = *(const float4*)(kg + (hb + jr * 4 + x) * Ksz + c0);
            float4 vr = *(const float4*)(vg + (hb + jr * 4 + x) * Vsz + c0);
            ka[x][0] = kr.x; ka[x][1] = kr.y; ka[x][2] = kr.z; ka[x][3] = kr.w;
            va[x][0] = vr.x; va[x][1] = vr.y; va[x][2] = vr.z; va[x][3] = vr.w;
        }
        #pragma unroll
        for (int y = 0; y < 4; ++y) {
            u16x4 h, w;
            float psum = 0.f;
            #pragma unroll
            for (int x = 0; x < 4; ++x) {
                float f = ka[x][y] * s4[x];
                h[x] = f2bf(f);
                psum += f;
                w[x] = f2bf(va[x][y]);
            }
            *(u16x4*)&kThi[c0 + y][jr * 4] = h;
            *(u16x4*)&vTs[c0 + y][jr * 4] = w;
            // reduce psum over the 4 lanes sharing (cb,y): lanes ^16, ^32
            psum += __shfl_xor(psum, 16, 64);
            psum += __shfl_xor(psum, 32, 64);
            if (kgrp == 0) nUp[c0 + y][wid] = psum;
        }
    }
    __syncthreads();

    // wave owns k-tiles {2*wid, 2*wid+1} x all 8 v-tiles; D[k][v]
    f32x4 acc[2][8];
    #pragma unroll
    for (int kt = 0; kt < 2; ++kt)
        #pragma unroll
        for (int vt = 0; vt < 8; ++vt) acc[kt][vt] = (f32x4){0.f, 0.f, 0.f, 0.f};
    #pragma unroll
    for (int ks = 0; ks < 2; ++ks) {
        #pragma unroll
        for (int kt = 0; kt < 2; ++kt) {
            short8v af = *(const short8v*)&kThi[(wid * 2 + kt) * 16 + lrow][ks * 32 + kgrp * 8];
            #pragma unroll
            for (int vt = 0; vt < 8; ++vt) {
                short8v bv = *(const short8v*)&vTs[vt * 16 + lrow][ks * 32 + kgrp * 8];
                acc[kt][vt] = __builtin_amdgcn_mfma_f32_16x16x32_bf16(af, bv, acc[kt][vt], 0, 0, 0);
            }
        }
    }
    unsigned short* Ub = UT + (size_t)(bh * NT + c) * (Ksz * Vsz);
    #pragma unroll
    for (int kt = 0; kt < 2; ++kt) {
        int ktile = wid * 2 + kt;
        #pragma unroll
        for (int vt = 0; vt < 8; ++vt) {
            u16x4 w;
            #pragma unroll
            for (int r = 0; r < 4; ++r) w[r] = f2bf(acc[kt][vt][r]);
            *(u16x4*)(Ub + ((size_t)(ktile * 8 + vt) * 64 + lane) * 4) = w;
        }
    }
    if (tid < Ksz) {
        float s = nUp[tid][0] + nUp[tid][1] + nUp[tid][2] + nUp[tid][3];
        nU[(size_t)(bh * NT + c) * Ksz + tid] = s;
    }
}

// ---------------- kernel 4: flat state scan (U->Cp in place) + fused normalizer scan ----------------
__global__ __launch_bounds__(128) void k_scan(
    unsigned short* __restrict__ UT, const float* __restrict__ dec,
    const float* __restrict__ nU, float* __restrict__ np)
{
    int s = blockIdx.x, bh = blockIdx.y, tid = threadIdx.x;
    __shared__ float decs[NT];
    if (tid < NT) decs[tid] = dec[bh * NT + tid];
    __syncthreads();
    if (s == 32) {   // fused normalizer scan: tid = k index
        float n = 0.f;
        size_t base = (size_t)bh * NT * Ksz + tid;
        #pragma unroll 4
        for (int c2 = 0; c2 < NT; ++c2) {
            float u = nU[base + (size_t)c2 * Ksz];
            np[base + (size_t)c2 * Ksz] = n;
            n = n * decs[c2] + u;
        }
        return;
    }
    // layout-agnostic flat slice: 512 u16 per block, contiguous
    size_t base = (size_t)bh * NT * (Ksz * Vsz) + s * 512 + tid * 4;
    float C0 = 0.f, C1 = 0.f, C2 = 0.f, C3 = 0.f;
    #pragma unroll 4
    for (int c2 = 0; c2 < NT; ++c2) {
        size_t idx = base + (size_t)c2 * (Ksz * Vsz);
        u16x4 u = *(const u16x4*)(UT + idx);
        u16x4 w;
        w.x = f2bf(C0); w.y = f2bf(C1); w.z = f2bf(C2); w.w = f2bf(C3);
        *(u16x4*)(UT + idx) = w;
        float d = decs[c2];
        C0 = C0 * d + bf2f(u.x); C1 = C1 * d + bf2f(u.y);
        C2 = C2 * d + bf2f(u.z); C3 = C3 * d + bf2f(u.w);
    }
}

// ---------------- kernel 5: intra + consumption + normalize ----------------
// Phased LDS reuse: {khi,klo} -> {Sb,vT-swizzled} -> {Cp flat fragment-major}.
__global__ __launch_bounds__(256, 4) void k_intra(
    const float* __restrict__ qg, const float* __restrict__ kgl, const float* __restrict__ vg,
    const float* __restrict__ vecB, const float* __restrict__ vecI,
    const float* __restrict__ mintra, const float* __restrict__ mp,
    const float* __restrict__ np, const unsigned short* __restrict__ CpT,
    float* __restrict__ out)
{
    int c = blockIdx.x, bh = blockIdx.y, tid = threadIdx.x;
    int lane = tid & 63, wid = tid >> 6;
    int lrow = lane & 15, kgrp = lane >> 4;

    __shared__ __align__(16) unsigned short R[17408];   // 34816 B, phase-shared
    __shared__ float rowf[BT], colf[BT], sfqs[BT], emcs[BT], denb[BT], npv[Ksz];

    auto khi = (unsigned short(*)[136])R;               // phase A: [64][136]
    auto klo = (unsigned short(*)[136])(R + 64 * 136);
    auto Sb  = (unsigned short(*)[72])R;                // phase B: [64][72]
    unsigned short* vTf = R + 64 * 72;                  // phase B: v^T [128][64] XOR-swizzled
    unsigned short* cpsF = R;                           // phase C: flat fragment-major [16384]

    size_t hb = (size_t)bh * Tsz + (size_t)c * BT;
    float mpc = mp[bh * (NT + 1) + c];
    if (tid < BT) {
        float b = vecB[hb + tid];
        float mc = fmaxf(mpc + b, mintra[hb + tid]);
        rowf[tid] = SCALE * exp2f(b - mc);
        colf[tid] = exp2f(vecI[hb + tid] - b);
        sfqs[tid] = SCALE * exp2f(b + mpc - mc);
        emcs[tid] = exp2f(-mc);
    }
    if (tid < Ksz) npv[tid] = np[((size_t)bh * NT + c) * Ksz + tid];

    // ---- phase 1: stage k hi/lo; q -> regs; v prefetch (coalesced) ----
    const float4* k4 = (const float4*)(kgl + hb * Ksz);
    for (int e = tid; e < BT * Ksz / 4; e += 256) {
        int i = e >> 5, c4 = (e & 31) * 4;
        float4 kv = k4[e];
        u16x4 h, l;
        h.x = f2bf(kv.x); l.x = f2bf(kv.x - bf2f(h.x));
        h.y = f2bf(kv.y); l.y = f2bf(kv.y - bf2f(h.y));
        h.z = f2bf(kv.z); l.z = f2bf(kv.z - bf2f(h.z));
        h.w = f2bf(kv.w); l.w = f2bf(kv.w - bf2f(h.w));
        *(u16x4*)&khi[i][c4] = h; *(u16x4*)&klo[i][c4] = l;
    }
    const float* qrow = qg + (hb + wid * 16 + lrow) * Ksz;
    float qf[4][8];
    #pragma unroll
    for (int ks = 0; ks < 4; ++ks) {
        float4 a = *(const float4*)(qrow + ks * 32 + kgrp * 8);
        float4 b = *(const float4*)(qrow + ks * 32 + kgrp * 8 + 4);
        qf[ks][0] = a.x; qf[ks][1] = a.y; qf[ks][2] = a.z; qf[ks][3] = a.w;
        qf[ks][4] = b.x; qf[ks][5] = b.y; qf[ks][6] = b.z; qf[ks][7] = b.w;
    }
    int vcb = tid & 15, jb = tid >> 4;
    float vpre[2][4][4];
    #pragma unroll
    for (int p = 0; p < 2; ++p)
        #pragma unroll
        for (int x = 0; x < 4; ++x) {
            float4 r4 = *(const float4*)(vg + (hb + jb * 4 + x) * Vsz + p * 64 + vcb * 4);
            vpre[p][x][0] = r4.x; vpre[p][x][1] = r4.y; vpre[p][x][2] = r4.z; vpre[p][x][3] = r4.w;
        }
    __syncthreads();

    // ---- phase 2: denominator inter part + S = q k^T (3-way split) ----
    float dot = 0.f;
    #pragma unroll
    for (int ks = 0; ks < 4; ++ks)
        #pragma unroll
        for (int x = 0; x < 8; ++x) dot += qf[ks][x] * npv[ks * 32 + kgrp * 8 + x];
    dot += __shfl_xor(dot, 16, 64);
    dot += __shfl_xor(dot, 32, 64);
    float qdot = sfqs[wid * 16 + lrow] * dot;

    short8v qh[4], ql[4];
    #pragma unroll
    for (int ks = 0; ks < 4; ++ks)
        #pragma unroll
        for (int x = 0; x < 8; ++x) {
            float f = qf[ks][x];
            unsigned short hh = f2bf(f);
            qh[ks][x] = (short)hh;
            ql[ks][x] = (short)f2bf(f - bf2f(hh));
        }

    f32x4 accS[4];
    #pragma unroll
    for (int jt = 0; jt < 4; ++jt) accS[jt] = (f32x4){0.f, 0.f, 0.f, 0.f};
    #pragma unroll
    for (int ks = 0; ks < 4; ++ks) {
        #pragma unroll
        for (int jt = 0; jt < 4; ++jt) {
            if (jt <= wid) {
                short8v bh_ = *(const short8v*)&khi[jt * 16 + lrow][ks * 32 + kgrp * 8];
                short8v bl  = *(const short8v*)&klo[jt * 16 + lrow][ks * 32 + kgrp * 8];
                accS[jt] = __builtin_amdgcn_mfma_f32_16x16x32_bf16(qh[ks], bh_, accS[jt], 0, 0, 0);
                accS[jt] = __builtin_amdgcn_mfma_f32_16x16x32_bf16(ql[ks], bh_, accS[jt], 0, 0, 0);
                accS[jt] = __builtin_amdgcn_mfma_f32_16x16x32_bf16(qh[ks], bl,  accS[jt], 0, 0, 0);
            }
        }
    }

    float rsum[4] = {0.f, 0.f, 0.f, 0.f};
    unsigned short sreg[4][4];
    #pragma unroll
    for (int jt = 0; jt < 4; ++jt)
        #pragma unroll
        for (int r = 0; r < 4; ++r) {
            int i = wid * 16 + kgrp * 4 + r, j = jt * 16 + lrow;
            float val = (j <= i) ? accS[jt][r] * rowf[i] * colf[j] : 0.f;
            rsum[r] += val;
            sreg[jt][r] = f2bf(val);
        }
    #pragma unroll
    for (int r = 0; r < 4; ++r) {
        rsum[r] += __shfl_xor(rsum[r], 1, 64);
        rsum[r] += __shfl_xor(rsum[r], 2, 64);
        rsum[r] += __shfl_xor(rsum[r], 4, 64);
        rsum[r] += __shfl_xor(rsum[r], 8, 64);
    }
    float qd[4];
    #pragma unroll
    for (int r = 0; r < 4; ++r) qd[r] = __shfl(qdot, kgrp * 4 + r, 64);
    if (lrow == 0) {
        #pragma unroll
        for (int r = 0; r < 4; ++r) {
            int i = wid * 16 + kgrp * 4 + r;
            float den = qd[r] + rsum[r];
            denb[i] = 1.f / fmaxf(fabsf(den), emcs[i]);
        }
    }
    __syncthreads();   // phase-A reads of khi/klo complete

    // ---- phase 3: write Sb + swizzled vT; issue Cp prefetch (flat) ----
    const u16x8* Cg = (const u16x8*)(CpT + ((size_t)bh * NT + c) * (Ksz * Vsz));
    u16x8 cpre[8];
    #pragma unroll
    for (int p2 = 0; p2 < 8; ++p2) cpre[p2] = Cg[tid + p2 * 256];  // in flight during PV

    #pragma unroll
    for (int jt = 0; jt < 4; ++jt)
        #pragma unroll
        for (int r = 0; r < 4; ++r)
            Sb[wid * 16 + kgrp * 4 + r][jt * 16 + lrow] = sreg[jt][r];
    #pragma unroll
    for (int p = 0; p < 2; ++p)
        #pragma unroll
        for (int y = 0; y < 4; ++y) {
            int row = p * 64 + vcb * 4 + y;
            int swzb = (jb * 8) ^ ((row & 7) << 4);   // byte offset, XOR-16B swizzle
            u16x4 w;
            #pragma unroll
            for (int x = 0; x < 4; ++x) w[x] = f2bf(vpre[p][x][y]);
            *(u16x4*)((char*)(vTf + row * 64) + swzb) = w;
        }
    __syncthreads();

    // ---- phase 4: PV = S @ v via MFMA (swizzled vT reads) ----
    f32x4 accV[8];
    #pragma unroll
    for (int vt = 0; vt < 8; ++vt) accV[vt] = (f32x4){0.f, 0.f, 0.f, 0.f};
    #pragma unroll
    for (int ks = 0; ks < 2; ++ks) {
        short8v as_ = *(const short8v*)&Sb[wid * 16 + lrow][ks * 32 + kgrp * 8];
        #pragma unroll
        for (int vt = 0; vt < 8; ++vt) {
            int row = vt * 16 + lrow;
            int swzb = ((ks * 64 + kgrp * 16)) ^ ((row & 7) << 4);
            short8v bv = *(const short8v*)((const char*)(vTf + row * 64) + swzb);
            accV[vt] = __builtin_amdgcn_mfma_f32_16x16x32_bf16(as_, bv, accV[vt], 0, 0, 0);
        }
    }
    __syncthreads();   // phase-B reads of Sb/vT complete

    // ---- phase 5: stage Cp flat (straight copy from prefetch regs) ----
    #pragma unroll
    for (int p2 = 0; p2 < 8; ++p2) {
        int idx = tid + p2 * 256;
        *(u16x8*)&cpsF[idx * 8] = cpre[p2];
    }
    __syncthreads();

    // ---- phase 6: inter = q @ Cp from fragment-major LDS + combine + store ----
    f32x4 accC[8];
    #pragma unroll
    for (int vt = 0; vt < 8; ++vt) accC[vt] = (f32x4){0.f, 0.f, 0.f, 0.f};
    #pragma unroll
    for (int ks = 0; ks < 4; ++ks) {
        int ktile = ks * 2 + (kgrp >> 1);
        int lsrc = (kgrp & 1) * 32 + lrow;
        #pragma unroll
        for (int vt = 0; vt < 8; ++vt) {
            const unsigned short* pf = &cpsF[((ktile * 8 + vt) * 64 + lsrc) * 4];
            u16x4 lo4 = *(const u16x4*)pf;
            u16x4 hi4 = *(const u16x4*)(pf + 64);
            short8v bc;
            bc[0] = (short)lo4.x; bc[1] = (short)lo4.y; bc[2] = (short)lo4.z; bc[3] = (short)lo4.w;
            bc[4] = (short)hi4.x; bc[5] = (short)hi4.y; bc[6] = (short)hi4.z; bc[7] = (short)hi4.w;
            accC[vt] = __builtin_amdgcn_mfma_f32_16x16x32_bf16(qh[ks], bc, accC[vt], 0, 0, 0);
            accC[vt] = __builtin_amdgcn_mfma_f32_16x16x32_bf16(ql[ks], bc, accC[vt], 0, 0, 0);
        }
    }
    size_t gb = hb * Vsz;
    #pragma unroll
    for (int vt = 0; vt < 8; ++vt)
        #pragma unroll
        for (int r = 0; r < 4; ++r) {
            int i = wid * 16 + kgrp * 4 + r, vc = vt * 16 + lrow;
            out[gb + (size_t)i * Vsz + vc] = (sfqs[i] * accC[vt][r] + accV[vt][r]) * denb[i];
        }
}

extern "C" void kernel_launch(void* const* d_in, const int* in_sizes, int n_in,
                              void* d_out, int out_size, void* d_ws, size_t ws_size,
                              hipStream_t stream) {
    const float* q  = (const float*)d_in[0];
    const float* k  = (const float*)d_in[1];
    const float* v  = (const float*)d_in[2];
    const float* ig = (const float*)d_in[3];
    const float* fg = (const float*)d_in[4];
    float* out = (float*)d_out;

    float* ws = (float*)d_ws;
    float* vecB   = ws;                       // BH*T
    float* vecI   = vecB + BH * Tsz;          // BH*T
    float* vecA   = vecI + BH * Tsz;          // BH*T
    float* mintra = vecA + BH * Tsz;          // BH*T
    float* scaG   = mintra + BH * Tsz;        // BH*NT
    float* scaA   = scaG + BH * NT;           // BH*NT
    float* dec    = scaA + BH * NT;           // BH*NT
    float* mp     = dec + BH * NT;            // BH*(NT+1)
    float* nU     = mp + BH * (NT + 1);       // BH*NT*K
    float* np     = nU + BH * NT * Ksz;       // BH*NT*K
    unsigned short* UT = (unsigned short*)(np + BH * NT * Ksz);  // BH*NT*K*V bf16 (in-place U->Cp)

    k_gates<<<dim3(NT, BH), 64, 0, stream>>>(ig, fg, vecB, vecI, vecA, mintra, scaG, scaA);
    k_mscan<<<dim3(BH), 64, 0, stream>>>(scaG, scaA, mp, dec);
    k_state<<<dim3(NT, BH), 256, 0, stream>>>(k, v, vecA, mp, UT, nU);
    k_scan<<<dim3(33, BH), 128, 0, stream>>>(UT, dec, nU, np);
    k_intra<<<dim3(NT, BH), 256, 0, stream>>>(q, k, v, vecB, vecI, mintra, mp, np, UT, out);
}

// Round 9
// 119.730 us; speedup vs baseline: 1.2009x; 1.0007x over previous
//
#include <hip/hip_runtime.h>
#include <hip/hip_bf16.h>
#include <math.h>

// mLSTM chunked forward. Round 9: k_state LDS XOR-16B swizzle (both sides) to kill
// the 8-way staging-write bank conflict. Everything else identical to round 8.
// B=4 H=8 T=4096 K=V=128, BT=64, NT=64.

#define LOG2E 1.4426950408889634f
constexpr int Bsz = 4, Hsz = 8, Tsz = 4096, Ksz = 128, Vsz = 128;
constexpr int BT = 64, NT = 64, BH = Bsz * Hsz;
constexpr float SCALE = 0.08838834764831845f; // 128^-0.5

typedef __attribute__((ext_vector_type(8))) short short8v;   // MFMA A/B frag (8 bf16)
typedef __attribute__((ext_vector_type(4))) float f32x4;     // MFMA C/D frag
typedef __attribute__((ext_vector_type(4))) unsigned short u16x4;
typedef __attribute__((ext_vector_type(8))) unsigned short u16x8;

__device__ inline float bf2f(unsigned short u) {
    union { unsigned int i; float f; } c; c.i = ((unsigned int)u) << 16; return c.f;
}
__device__ inline unsigned short f2bf(float f) {
    __hip_bfloat16 h = __float2bfloat16(f);            // HW v_cvt (RNE)
    union { __hip_bfloat16 b; unsigned short u; } cv; cv.b = h; return cv.u;
}

// ---------------- kernel 1: gate preprocessing per (bh, chunk) ----------------
__global__ __launch_bounds__(64) void k_gates(
    const float* __restrict__ ig, const float* __restrict__ fg,
    float* __restrict__ vecB, float* __restrict__ vecI, float* __restrict__ vecA,
    float* __restrict__ mintra, float* __restrict__ scaG, float* __restrict__ scaA)
{
    int c = blockIdx.x, bh = blockIdx.y, lane = threadIdx.x;
    int t = bh * Tsz + c * BT + lane;
    float f = fg[t];
    float ls = fminf(f, 0.f) - log1pf(expf(-fabsf(f)));  // stable log_sigmoid
    float vF = ls * LOG2E;
    float vI = ig[t] * LOG2E;
    float b = vF;
    #pragma unroll
    for (int off = 1; off < 64; off <<= 1) {
        float o = __shfl_up(b, off, 64);
        if (lane >= off) b += o;
    }
    float g = __shfl(b, 63, 64);
    float mi = vI - b;
    #pragma unroll
    for (int off = 1; off < 64; off <<= 1) {
        float o = __shfl_up(mi, off, 64);
        if (lane >= off) mi = fmaxf(mi, o);
    }
    float a = vI + g - b;
    vecB[t] = b; vecI[t] = vI; vecA[t] = a; mintra[t] = b + mi;
    float am = a;
    #pragma unroll
    for (int off = 32; off; off >>= 1) am = fmaxf(am, __shfl_xor(am, off, 64));
    if (lane == 0) { scaG[bh * NT + c] = g; scaA[bh * NT + c] = am; }
}

// ---------------- kernel 2: m stabilizer scan + per-chunk decay ----------------
__global__ __launch_bounds__(64) void k_mscan(
    const float* __restrict__ scaG, const float* __restrict__ scaA,
    float* __restrict__ mp, float* __restrict__ dec)
{
    int bh = blockIdx.x, lane = threadIdx.x;
    float g0 = scaG[bh * NT + lane];
    float a = g0, b = scaA[bh * NT + lane];
    #pragma unroll
    for (int off = 1; off < 64; off <<= 1) {
        float ap = __shfl_up(a, off, 64);
        float bp = __shfl_up(b, off, 64);
        if (lane >= off) { b = fmaxf(bp + a, b); a = ap + a; }
    }
    float m_incl = fmaxf(a, b);
    float m_prev = __shfl_up(m_incl, 1, 64);
    if (lane == 0) { m_prev = 0.f; mp[bh * (NT + 1)] = 0.f; }
    mp[bh * (NT + 1) + lane + 1] = m_incl;
    dec[bh * NT + lane] = exp2f(g0 + m_prev - m_incl);
}

// ---------------- kernel 3: U = kbar^T @ v, fragment-major flat output ----------------
// LDS tiles kThi/vTs are XOR-16B swizzled: granule' = granule ^ ((row>>2)&7).
// Write rows are cb*4+y -> key = cb&7; reads apply the same key per fragment row.
__global__ __launch_bounds__(256, 4) void k_state(
    const float* __restrict__ kg, const float* __restrict__ vg,
    const float* __restrict__ vecA, const float* __restrict__ mp,
    unsigned short* __restrict__ UT, float* __restrict__ nU)
{
    int c = blockIdx.x, bh = blockIdx.y, tid = threadIdx.x;
    int lane = tid & 63, wid = tid >> 6;
    int lrow = lane & 15, kgrp = lane >> 4;

    __shared__ __align__(16) unsigned short kThi[128][72];  // kbar^T [k][j], swizzled
    __shared__ __align__(16) unsigned short vTs[128][72];   // v^T    [v][j], swizzled
    __shared__ float nUp[128][5];                           // per-wave fp32 partials

    size_t hb = (size_t)bh * Tsz + (size_t)c * BT;
    float mpn = mp[bh * (NT + 1) + c + 1];

    int cb = tid & 15, jr = tid >> 4;   // cb: col-block (coalesced global), jr: j-block
    int wboff = (((jr >> 1) ^ (cb & 7)) * 16) + (jr & 1) * 8;  // swizzled byte offset
    float s4[4];
    #pragma unroll
    for (int x = 0; x < 4; ++x) s4[x] = exp2f(vecA[hb + jr * 4 + x] - mpn);
    #pragma unroll
    for (int p = 0; p < 2; ++p) {
        int c0 = p * 64 + cb * 4;
        float ka[4][4], va[4][4];
        #pragma unroll
        for (int x = 0; x < 4; ++x) {
            float4 kr = *(const float4*)(kg + (hb + jr * 4 + x) * Ksz + c0);
            float4 vr = *(const float4*)(vg + (hb + jr * 4 + x) * Vsz + c0);
            ka[x][0] = kr.x; ka[x][1] = kr.y; ka[x][2] = kr.z; ka[x][3] = kr.w;
            va[x][0] = vr.x; va[x][1] = vr.y; va[x][2] = vr.z; va[x][3] = vr.w;
        }
        #pragma unroll
        for (int y = 0; y < 4; ++y) {
            u16x4 h, w;
            float psum = 0.f;
            #pragma unroll
            for (int x = 0; x < 4; ++x) {
                float f = ka[x][y] * s4[x];
                h[x] = f2bf(f);
                psum += f;
                w[x] = f2bf(va[x][y]);
            }
            *(u16x4*)((char*)&kThi[c0 + y][0] + wboff) = h;
            *(u16x4*)((char*)&vTs[c0 + y][0] + wboff) = w;
            // reduce psum over the 4 lanes sharing (cb,y): lanes ^16, ^32
            psum += __shfl_xor(psum, 16, 64);
            psum += __shfl_xor(psum, 32, 64);
            if (kgrp == 0) nUp[c0 + y][wid] = psum;
        }
    }
    __syncthreads();

    // wave owns k-tiles {2*wid, 2*wid+1} x all 8 v-tiles; D[k][v]
    f32x4 acc[2][8];
    #pragma unroll
    for (int kt = 0; kt < 2; ++kt)
        #pragma unroll
        for (int vt = 0; vt < 8; ++vt) acc[kt][vt] = (f32x4){0.f, 0.f, 0.f, 0.f};
    #pragma unroll
    for (int ks = 0; ks < 2; ++ks) {
        int G = ks * 4 + kgrp;          // 16B granule index within the 128B j-span
        #pragma unroll
        for (int kt = 0; kt < 2; ++kt) {
            int arow = (wid * 2 + kt) * 16 + lrow;
            short8v af = *(const short8v*)((const char*)&kThi[arow][0]
                                           + ((G ^ ((arow >> 2) & 7)) * 16));
            #pragma unroll
            for (int vt = 0; vt < 8; ++vt) {
                int brow = vt * 16 + lrow;
                short8v bv = *(const short8v*)((const char*)&vTs[brow][0]
                                               + ((G ^ ((brow >> 2) & 7)) * 16));
                acc[kt][vt] = __builtin_amdgcn_mfma_f32_16x16x32_bf16(af, bv, acc[kt][vt], 0, 0, 0);
            }
        }
    }
    unsigned short* Ub = UT + (size_t)(bh * NT + c) * (Ksz * Vsz);
    #pragma unroll
    for (int kt = 0; kt < 2; ++kt) {
        int ktile = wid * 2 + kt;
        #pragma unroll
        for (int vt = 0; vt < 8; ++vt) {
            u16x4 w;
            #pragma unroll
            for (int r = 0; r < 4; ++r) w[r] = f2bf(acc[kt][vt][r]);
            *(u16x4*)(Ub + ((size_t)(ktile * 8 + vt) * 64 + lane) * 4) = w;
        }
    }
    if (tid < Ksz) {
        float s = nUp[tid][0] + nUp[tid][1] + nUp[tid][2] + nUp[tid][3];
        nU[(size_t)(bh * NT + c) * Ksz + tid] = s;
    }
}

// ---------------- kernel 4: flat state scan (U->Cp in place) + fused normalizer scan ----------------
__global__ __launch_bounds__(128) void k_scan(
    unsigned short* __restrict__ UT, const float* __restrict__ dec,
    const float* __restrict__ nU, float* __restrict__ np)
{
    int s = blockIdx.x, bh = blockIdx.y, tid = threadIdx.x;
    __shared__ float decs[NT];
    if (tid < NT) decs[tid] = dec[bh * NT + tid];
    __syncthreads();
    if (s == 32) {   // fused normalizer scan: tid = k index
        float n = 0.f;
        size_t base = (size_t)bh * NT * Ksz + tid;
        #pragma unroll 4
        for (int c2 = 0; c2 < NT; ++c2) {
            float u = nU[base + (size_t)c2 * Ksz];
            np[base + (size_t)c2 * Ksz] = n;
            n = n * decs[c2] + u;
        }
        return;
    }
    // layout-agnostic flat slice: 512 u16 per block, contiguous
    size_t base = (size_t)bh * NT * (Ksz * Vsz) + s * 512 + tid * 4;
    float C0 = 0.f, C1 = 0.f, C2 = 0.f, C3 = 0.f;
    #pragma unroll 4
    for (int c2 = 0; c2 < NT; ++c2) {
        size_t idx = base + (size_t)c2 * (Ksz * Vsz);
        u16x4 u = *(const u16x4*)(UT + idx);
        u16x4 w;
        w.x = f2bf(C0); w.y = f2bf(C1); w.z = f2bf(C2); w.w = f2bf(C3);
        *(u16x4*)(UT + idx) = w;
        float d = decs[c2];
        C0 = C0 * d + bf2f(u.x); C1 = C1 * d + bf2f(u.y);
        C2 = C2 * d + bf2f(u.z); C3 = C3 * d + bf2f(u.w);
    }
}

// ---------------- kernel 5: intra + consumption + normalize ----------------
// Phased LDS reuse: {khi,klo} -> {Sb,vT-swizzled} -> {Cp flat fragment-major}.
__global__ __launch_bounds__(256, 4) void k_intra(
    const float* __restrict__ qg, const float* __restrict__ kgl, const float* __restrict__ vg,
    const float* __restrict__ vecB, const float* __restrict__ vecI,
    const float* __restrict__ mintra, const float* __restrict__ mp,
    const float* __restrict__ np, const unsigned short* __restrict__ CpT,
    float* __restrict__ out)
{
    int c = blockIdx.x, bh = blockIdx.y, tid = threadIdx.x;
    int lane = tid & 63, wid = tid >> 6;
    int lrow = lane & 15, kgrp = lane >> 4;

    __shared__ __align__(16) unsigned short R[17408];   // 34816 B, phase-shared
    __shared__ float rowf[BT], colf[BT], sfqs[BT], emcs[BT], denb[BT], npv[Ksz];

    auto khi = (unsigned short(*)[136])R;               // phase A: [64][136]
    auto klo = (unsigned short(*)[136])(R + 64 * 136);
    auto Sb  = (unsigned short(*)[72])R;                // phase B: [64][72]
    unsigned short* vTf = R + 64 * 72;                  // phase B: v^T [128][64] XOR-swizzled
    unsigned short* cpsF = R;                           // phase C: flat fragment-major [16384]

    size_t hb = (size_t)bh * Tsz + (size_t)c * BT;
    float mpc = mp[bh * (NT + 1) + c];
    if (tid < BT) {
        float b = vecB[hb + tid];
        float mc = fmaxf(mpc + b, mintra[hb + tid]);
        rowf[tid] = SCALE * exp2f(b - mc);
        colf[tid] = exp2f(vecI[hb + tid] - b);
        sfqs[tid] = SCALE * exp2f(b + mpc - mc);
        emcs[tid] = exp2f(-mc);
    }
    if (tid < Ksz) npv[tid] = np[((size_t)bh * NT + c) * Ksz + tid];

    // ---- phase 1: stage k hi/lo; q -> regs; v prefetch (coalesced) ----
    const float4* k4 = (const float4*)(kgl + hb * Ksz);
    for (int e = tid; e < BT * Ksz / 4; e += 256) {
        int i = e >> 5, c4 = (e & 31) * 4;
        float4 kv = k4[e];
        u16x4 h, l;
        h.x = f2bf(kv.x); l.x = f2bf(kv.x - bf2f(h.x));
        h.y = f2bf(kv.y); l.y = f2bf(kv.y - bf2f(h.y));
        h.z = f2bf(kv.z); l.z = f2bf(kv.z - bf2f(h.z));
        h.w = f2bf(kv.w); l.w = f2bf(kv.w - bf2f(h.w));
        *(u16x4*)&khi[i][c4] = h; *(u16x4*)&klo[i][c4] = l;
    }
    const float* qrow = qg + (hb + wid * 16 + lrow) * Ksz;
    float qf[4][8];
    #pragma unroll
    for (int ks = 0; ks < 4; ++ks) {
        float4 a = *(const float4*)(qrow + ks * 32 + kgrp * 8);
        float4 b = *(const float4*)(qrow + ks * 32 + kgrp * 8 + 4);
        qf[ks][0] = a.x; qf[ks][1] = a.y; qf[ks][2] = a.z; qf[ks][3] = a.w;
        qf[ks][4] = b.x; qf[ks][5] = b.y; qf[ks][6] = b.z; qf[ks][7] = b.w;
    }
    int vcb = tid & 15, jb = tid >> 4;
    float vpre[2][4][4];
    #pragma unroll
    for (int p = 0; p < 2; ++p)
        #pragma unroll
        for (int x = 0; x < 4; ++x) {
            float4 r4 = *(const float4*)(vg + (hb + jb * 4 + x) * Vsz + p * 64 + vcb * 4);
            vpre[p][x][0] = r4.x; vpre[p][x][1] = r4.y; vpre[p][x][2] = r4.z; vpre[p][x][3] = r4.w;
        }
    __syncthreads();

    // ---- phase 2: denominator inter part + S = q k^T (3-way split) ----
    float dot = 0.f;
    #pragma unroll
    for (int ks = 0; ks < 4; ++ks)
        #pragma unroll
        for (int x = 0; x < 8; ++x) dot += qf[ks][x] * npv[ks * 32 + kgrp * 8 + x];
    dot += __shfl_xor(dot, 16, 64);
    dot += __shfl_xor(dot, 32, 64);
    float qdot = sfqs[wid * 16 + lrow] * dot;

    short8v qh[4], ql[4];
    #pragma unroll
    for (int ks = 0; ks < 4; ++ks)
        #pragma unroll
        for (int x = 0; x < 8; ++x) {
            float f = qf[ks][x];
            unsigned short hh = f2bf(f);
            qh[ks][x] = (short)hh;
            ql[ks][x] = (short)f2bf(f - bf2f(hh));
        }

    f32x4 accS[4];
    #pragma unroll
    for (int jt = 0; jt < 4; ++jt) accS[jt] = (f32x4){0.f, 0.f, 0.f, 0.f};
    #pragma unroll
    for (int ks = 0; ks < 4; ++ks) {
        #pragma unroll
        for (int jt = 0; jt < 4; ++jt) {
            if (jt <= wid) {
                short8v bh_ = *(const short8v*)&khi[jt * 16 + lrow][ks * 32 + kgrp * 8];
                short8v bl  = *(const short8v*)&klo[jt * 16 + lrow][ks * 32 + kgrp * 8];
                accS[jt] = __builtin_amdgcn_mfma_f32_16x16x32_bf16(qh[ks], bh_, accS[jt], 0, 0, 0);
                accS[jt] = __builtin_amdgcn_mfma_f32_16x16x32_bf16(ql[ks], bh_, accS[jt], 0, 0, 0);
                accS[jt] = __builtin_amdgcn_mfma_f32_16x16x32_bf16(qh[ks], bl,  accS[jt], 0, 0, 0);
            }
        }
    }

    float rsum[4] = {0.f, 0.f, 0.f, 0.f};
    unsigned short sreg[4][4];
    #pragma unroll
    for (int jt = 0; jt < 4; ++jt)
        #pragma unroll
        for (int r = 0; r < 4; ++r) {
            int i = wid * 16 + kgrp * 4 + r, j = jt * 16 + lrow;
            float val = (j <= i) ? accS[jt][r] * rowf[i] * colf[j] : 0.f;
            rsum[r] += val;
            sreg[jt][r] = f2bf(val);
        }
    #pragma unroll
    for (int r = 0; r < 4; ++r) {
        rsum[r] += __shfl_xor(rsum[r], 1, 64);
        rsum[r] += __shfl_xor(rsum[r], 2, 64);
        rsum[r] += __shfl_xor(rsum[r], 4, 64);
        rsum[r] += __shfl_xor(rsum[r], 8, 64);
    }
    float qd[4];
    #pragma unroll
    for (int r = 0; r < 4; ++r) qd[r] = __shfl(qdot, kgrp * 4 + r, 64);
    if (lrow == 0) {
        #pragma unroll
        for (int r = 0; r < 4; ++r) {
            int i = wid * 16 + kgrp * 4 + r;
            float den = qd[r] + rsum[r];
            denb[i] = 1.f / fmaxf(fabsf(den), emcs[i]);
        }
    }
    __syncthreads();   // phase-A reads of khi/klo complete

    // ---- phase 3: write Sb + swizzled vT; issue Cp prefetch (flat) ----
    const u16x8* Cg = (const u16x8*)(CpT + ((size_t)bh * NT + c) * (Ksz * Vsz));
    u16x8 cpre[8];
    #pragma unroll
    for (int p2 = 0; p2 < 8; ++p2) cpre[p2] = Cg[tid + p2 * 256];  // in flight during PV

    #pragma unroll
    for (int jt = 0; jt < 4; ++jt)
        #pragma unroll
        for (int r = 0; r < 4; ++r)
            Sb[wid * 16 + kgrp * 4 + r][jt * 16 + lrow] = sreg[jt][r];
    #pragma unroll
    for (int p = 0; p < 2; ++p)
        #pragma unroll
        for (int y = 0; y < 4; ++y) {
            int row = p * 64 + vcb * 4 + y;
            int swzb = (jb * 8) ^ ((row & 7) << 4);   // byte offset, XOR-16B swizzle
            u16x4 w;
            #pragma unroll
            for (int x = 0; x < 4; ++x) w[x] = f2bf(vpre[p][x][y]);
            *(u16x4*)((char*)(vTf + row * 64) + swzb) = w;
        }
    __syncthreads();

    // ---- phase 4: PV = S @ v via MFMA (swizzled vT reads) ----
    f32x4 accV[8];
    #pragma unroll
    for (int vt = 0; vt < 8; ++vt) accV[vt] = (f32x4){0.f, 0.f, 0.f, 0.f};
    #pragma unroll
    for (int ks = 0; ks < 2; ++ks) {
        short8v as_ = *(const short8v*)&Sb[wid * 16 + lrow][ks * 32 + kgrp * 8];
        #pragma unroll
        for (int vt = 0; vt < 8; ++vt) {
            int row = vt * 16 + lrow;
            int swzb = ((ks * 64 + kgrp * 16)) ^ ((row & 7) << 4);
            short8v bv = *(const short8v*)((const char*)(vTf + row * 64) + swzb);
            accV[vt] = __builtin_amdgcn_mfma_f32_16x16x32_bf16(as_, bv, accV[vt], 0, 0, 0);
        }
    }
    __syncthreads();   // phase-B reads of Sb/vT complete

    // ---- phase 5: stage Cp flat (straight copy from prefetch regs) ----
    #pragma unroll
    for (int p2 = 0; p2 < 8; ++p2) {
        int idx = tid + p2 * 256;
        *(u16x8*)&cpsF[idx * 8] = cpre[p2];
    }
    __syncthreads();

    // ---- phase 6: inter = q @ Cp from fragment-major LDS + combine + store ----
    f32x4 accC[8];
    #pragma unroll
    for (int vt = 0; vt < 8; ++vt) accC[vt] = (f32x4){0.f, 0.f, 0.f, 0.f};
    #pragma unroll
    for (int ks = 0; ks < 4; ++ks) {
        int ktile = ks * 2 + (kgrp >> 1);
        int lsrc = (kgrp & 1) * 32 + lrow;
        #pragma unroll
        for (int vt = 0; vt < 8; ++vt) {
            const unsigned short* pf = &cpsF[((ktile * 8 + vt) * 64 + lsrc) * 4];
            u16x4 lo4 = *(const u16x4*)pf;
            u16x4 hi4 = *(const u16x4*)(pf + 64);
            short8v bc;
            bc[0] = (short)lo4.x; bc[1] = (short)lo4.y; bc[2] = (short)lo4.z; bc[3] = (short)lo4.w;
            bc[4] = (short)hi4.x; bc[5] = (short)hi4.y; bc[6] = (short)hi4.z; bc[7] = (short)hi4.w;
            accC[vt] = __builtin_amdgcn_mfma_f32_16x16x32_bf16(qh[ks], bc, accC[vt], 0, 0, 0);
            accC[vt] = __builtin_amdgcn_mfma_f32_16x16x32_bf16(ql[ks], bc, accC[vt], 0, 0, 0);
        }
    }
    size_t gb = hb * Vsz;
    #pragma unroll
    for (int vt = 0; vt < 8; ++vt)
        #pragma unroll
        for (int r = 0; r < 4; ++r) {
            int i = wid * 16 + kgrp * 4 + r, vc = vt * 16 + lrow;
            out[gb + (size_t)i * Vsz + vc] = (sfqs[i] * accC[vt][r] + accV[vt][r]) * denb[i];
        }
}

extern "C" void kernel_launch(void* const* d_in, const int* in_sizes, int n_in,
                              void* d_out, int out_size, void* d_ws, size_t ws_size,
                              hipStream_t stream) {
    const float* q  = (const float*)d_in[0];
    const float* k  = (const float*)d_in[1];
    const float* v  = (const float*)d_in[2];
    const float* ig = (const float*)d_in[3];
    const float* fg = (const float*)d_in[4];
    float* out = (float*)d_out;

    float* ws = (float*)d_ws;
    float* vecB   = ws;                       // BH*T
    float* vecI   = vecB + BH * Tsz;          // BH*T
    float* vecA   = vecI + BH * Tsz;          // BH*T
    float* mintra = vecA + BH * Tsz;          // BH*T
    float* scaG   = mintra + BH * Tsz;        // BH*NT
    float* scaA   = scaG + BH * NT;           // BH*NT
    float* dec    = scaA + BH * NT;           // BH*NT
    float* mp     = dec + BH * NT;            // BH*(NT+1)
    float* nU     = mp + BH * (NT + 1);       // BH*NT*K
    float* np     = nU + BH * NT * Ksz;       // BH*NT*K
    unsigned short* UT = (unsigned short*)(np + BH * NT * Ksz);  // BH*NT*K*V bf16 (in-place U->Cp)

    k_gates<<<dim3(NT, BH), 64, 0, stream>>>(ig, fg, vecB, vecI, vecA, mintra, scaG, scaA);
    k_mscan<<<dim3(BH), 64, 0, stream>>>(scaG, scaA, mp, dec);
    k_state<<<dim3(NT, BH), 256, 0, stream>>>(k, v, vecA, mp, UT, nU);
    k_scan<<<dim3(33, BH), 128, 0, stream>>>(UT, dec, nU, np);
    k_intra<<<dim3(NT, BH), 256, 0, stream>>>(q, k, v, vecB, vecI, mintra, mp, np, UT, out);
}